// Round 3
// baseline (3079.589 us; speedup 1.0000x reference)
//
#include <hip/hip_runtime.h>
#include <hip/hip_bf16.h>

typedef unsigned short u16;
typedef unsigned int u32;
typedef __attribute__((ext_vector_type(8))) short short8;  // bf16x8 MFMA A/B frag
typedef __attribute__((ext_vector_type(4))) float f32x4;   // MFMA acc / float4
typedef __attribute__((ext_vector_type(4))) int i32x4;     // 16B vector ld/st

__device__ __forceinline__ float b2f(u16 u) {
    union { u32 i; float f; } x; x.i = ((u32)u) << 16; return x.f;
}
__device__ __forceinline__ u16 f2b(float f) {
    union { float f; u32 u; } x; x.f = f;
    u32 r = x.u + 0x7fffu + ((x.u >> 16) & 1u);
    return (u16)(r >> 16);
}

// ---------------------------------------------------------------------------
// Dtype probe: interpret first 512 u16 of x as bf16. fp32 data -> low-halves
// have random exponents -> some |v|>1e6 or NaN with overwhelming probability.
// flag = 1 (fp32 wire) / 0 (bf16 wire).
// ---------------------------------------------------------------------------
__global__ void probe_dtype(const u16* __restrict__ x, int* __restrict__ flag) {
    int bigf = 0;
    for (int i = threadIdx.x; i < 512; i += 64) {
        float v = fabsf(b2f(x[i]));
        if (!(v <= 1e6f)) bigf = 1;   // catches huge AND NaN
    }
    int any = __any(bigf);
    if (threadIdx.x == 0) *flag = any ? 1 : 0;
}

// ---------------------------------------------------------------------------
// Canonicalize input tensor to bf16: fp32 -> round; bf16 -> copy.
// 8 elements per thread, exact grids (n % 2048 == 0).
// ---------------------------------------------------------------------------
__global__ __launch_bounds__(256) void canon(
    const void* __restrict__ src, u16* __restrict__ dst, int n,
    const int* __restrict__ flag)
{
    int i = (blockIdx.x * 256 + threadIdx.x) * 8;
    if (i >= n) return;
    if (*flag) {
        const float* s = (const float*)src + i;
        f32x4 a = *(const f32x4*)s;
        f32x4 b = *(const f32x4*)(s + 4);
        union { i32x4 v; u16 h[8]; } o;
        o.h[0] = f2b(a[0]); o.h[1] = f2b(a[1]); o.h[2] = f2b(a[2]); o.h[3] = f2b(a[3]);
        o.h[4] = f2b(b[0]); o.h[5] = f2b(b[1]); o.h[6] = f2b(b[2]); o.h[7] = f2b(b[3]);
        *(i32x4*)(dst + i) = o.v;
    } else {
        *(i32x4*)(dst + i) = *(const i32x4*)((const u16*)src + i);
    }
}

// ---------------------------------------------------------------------------
// GEMM: C[M,N] = A[M,K] * B[K,N], all bf16 (u16 bits), fp32 accumulate.
// 128x128 block tile, BK=32, 4 waves each computing 64x64 via 4x4 MFMA tiles.
// Fragment maps per HW-verified m89/m97.
// ---------------------------------------------------------------------------
__global__ __launch_bounds__(256) void gemm_bf16(
    const u16* __restrict__ A, const u16* __restrict__ B, u16* __restrict__ C,
    int M, int N, int K)
{
    __shared__ __align__(16) u16 lA[128 * 32];   // [m][k], k-contiguous
    __shared__ __align__(16) u16 lB[128 * 40];   // [n][k] transposed, stride 40
    const int tid  = threadIdx.x;
    const int lane = tid & 63;
    const int wave = tid >> 6;
    const int la = lane & 15;      // MFMA: A row / B col / D col
    const int qd = lane >> 4;      // quad
    const int m0 = blockIdx.x * 128, n0 = blockIdx.y * 128;
    const int wm = (wave & 1) * 64, wn = (wave >> 1) * 64;

    // zero the lB pad columns (k=32..39) once — never staged
    for (int i = tid; i < 128 * 8; i += 256) {
        int r = i >> 3, c = i & 7;
        lB[r * 40 + 32 + c] = 0;
    }

    f32x4 acc[4][4];
    const f32x4 fz = {0.f, 0.f, 0.f, 0.f};
#pragma unroll
    for (int i = 0; i < 4; ++i)
#pragma unroll
        for (int j = 0; j < 4; ++j) acc[i][j] = fz;

    const int bn  = tid & 127;         // B stage: n within tile
    const int bkh = (tid >> 7) << 4;   // 0 or 16

    for (int k0 = 0; k0 < K; k0 += 32) {
        __syncthreads();
#pragma unroll
        for (int p = 0; p < 2; ++p) {
            int slot = tid + p * 256;
            int row = slot >> 2, seg = (slot & 3) << 3;
            *(i32x4*)(lA + row * 32 + seg) =
                *(const i32x4*)(A + (size_t)(m0 + row) * K + k0 + seg);
        }
        {
            const u16* gp = B + (size_t)(k0 + bkh) * N + n0 + bn;
            union { i32x4 v[2]; u16 s[16]; } t;
#pragma unroll
            for (int j = 0; j < 16; ++j) t.s[j] = gp[(size_t)j * N];
            *(i32x4*)(lB + bn * 40 + bkh)     = t.v[0];
            *(i32x4*)(lB + bn * 40 + bkh + 8) = t.v[1];
        }
        __syncthreads();

        short8 af[4], bf[4];
#pragma unroll
        for (int i = 0; i < 4; ++i)
            af[i] = *(const short8*)(lA + (wm + i * 16 + la) * 32 + qd * 8);
#pragma unroll
        for (int j = 0; j < 4; ++j)
            bf[j] = *(const short8*)(lB + (wn + j * 16 + la) * 40 + qd * 8);
#pragma unroll
        for (int i = 0; i < 4; ++i)
#pragma unroll
            for (int j = 0; j < 4; ++j)
                acc[i][j] = __builtin_amdgcn_mfma_f32_16x16x32_bf16(
                    af[i], bf[j], acc[i][j], 0, 0, 0);
    }

#pragma unroll
    for (int i = 0; i < 4; ++i)
#pragma unroll
        for (int j = 0; j < 4; ++j)
#pragma unroll
            for (int r = 0; r < 4; ++r) {
                int row = m0 + wm + i * 16 + qd * 4 + r;
                int col = n0 + wn + j * 16 + la;
                C[(size_t)row * N + col] = f2b(acc[i][j][r]);
            }
}

// ---------------------------------------------------------------------------
// Flash-style causal attention, fp32 vector ALU. Block = 256 threads, 64
// q-rows of one (b,h). Sanitized: any non-finite logit -> NEG_BIG; epilogue
// output clamped finite (diagnostic guarantee).
// ---------------------------------------------------------------------------
#define S_LEN 2048
#define D3 3072
#define NEG_BIG (-30000.0f)

__global__ __launch_bounds__(256) void attn_fwd(
    const u16* __restrict__ qkv, u16* __restrict__ outp)
{
    __shared__ __align__(16) float Qs[64 * 68];  // fp32, pre-scaled by 1/8
    __shared__ __align__(16) float Ks[64 * 68];
    __shared__ __align__(16) float Ls[64 * 68];  // logits, then P (in place)
    __shared__ __align__(16) u16  Vs[64 * 72];   // bf16 raw
    __shared__ float Ms[64];       // running row max
    __shared__ float As[64];       // per-tile alpha
    __shared__ float Li[64];       // running row denom
    const int tid = threadIdx.x;
    const int qt  = 31 - blockIdx.x;   // big blocks first
    const int bh  = blockIdx.y;
    const int b = bh >> 4, h = bh & 15;
    const int q0 = qt * 64;
    const size_t rowb = (size_t)b * S_LEN * D3;
    const int hq  = h * 192;
    const int t15 = tid & 15;
    const int tg  = tid >> 4;

    float Oacc[4][4];
#pragma unroll
    for (int i = 0; i < 4; ++i)
#pragma unroll
        for (int j = 0; j < 4; ++j) Oacc[i][j] = 0.f;

    if (tid < 64) { Ms[tid] = NEG_BIG; As[tid] = 0.f; Li[tid] = 0.f; }
    for (int i = tid; i < 64 * 4; i += 256) {
        int r = i >> 2, c = 64 + (i & 3);
        Qs[r * 68 + c] = 0.f; Ks[r * 68 + c] = 0.f; Ls[r * 68 + c] = 0.f;
    }
    for (int i = tid; i < 64 * 8; i += 256) {
        int r = i >> 3, c = 64 + (i & 7);
        Vs[r * 72 + c] = 0;
    }

    // stage Q once (scaled by dh^-0.5 = 0.125)
#pragma unroll
    for (int p = 0; p < 2; ++p) {
        int slot = tid + p * 256;
        int row = slot >> 3, seg = (slot & 7) << 3;
        union { i32x4 v; u16 s[8]; } u;
        u.v = *(const i32x4*)(qkv + rowb + (size_t)(q0 + row) * D3 + hq + seg);
        f32x4 f0 = { b2f(u.s[0]) * 0.125f, b2f(u.s[1]) * 0.125f,
                     b2f(u.s[2]) * 0.125f, b2f(u.s[3]) * 0.125f };
        f32x4 f1 = { b2f(u.s[4]) * 0.125f, b2f(u.s[5]) * 0.125f,
                     b2f(u.s[6]) * 0.125f, b2f(u.s[7]) * 0.125f };
        *(f32x4*)(Qs + row * 68 + seg)     = f0;
        *(f32x4*)(Qs + row * 68 + seg + 4) = f1;
    }

    for (int kt = 0; kt <= qt; ++kt) {
        const int k0 = kt * 64;
        __syncthreads();
#pragma unroll
        for (int p = 0; p < 2; ++p) {
            int slot = tid + p * 256;
            int row = slot >> 3, seg = (slot & 7) << 3;
            const u16* gp = qkv + rowb + (size_t)(k0 + row) * D3 + hq + 64 + seg;
            union { i32x4 v; u16 s[8]; } u;
            u.v = *(const i32x4*)gp;
            f32x4 f0 = { b2f(u.s[0]), b2f(u.s[1]), b2f(u.s[2]), b2f(u.s[3]) };
            f32x4 f1 = { b2f(u.s[4]), b2f(u.s[5]), b2f(u.s[6]), b2f(u.s[7]) };
            *(f32x4*)(Ks + row * 68 + seg)     = f0;
            *(f32x4*)(Ks + row * 68 + seg + 4) = f1;
            *(i32x4*)(Vs + row * 72 + seg)     = *(const i32x4*)(gp + 64);
        }
        __syncthreads();

        float dacc[4][4];
#pragma unroll
        for (int i = 0; i < 4; ++i)
#pragma unroll
            for (int j = 0; j < 4; ++j) dacc[i][j] = 0.f;
        for (int d = 0; d < 64; d += 4) {
            f32x4 qv[4], kv[4];
#pragma unroll
            for (int qi = 0; qi < 4; ++qi)
                qv[qi] = *(const f32x4*)(Qs + (t15 + 16 * qi) * 68 + d);
#pragma unroll
            for (int ki = 0; ki < 4; ++ki)
                kv[ki] = *(const f32x4*)(Ks + (tg + 16 * ki) * 68 + d);
#pragma unroll
            for (int qi = 0; qi < 4; ++qi)
#pragma unroll
                for (int ki = 0; ki < 4; ++ki)
                    dacc[qi][ki] += qv[qi][0] * kv[ki][0] + qv[qi][1] * kv[ki][1]
                                  + qv[qi][2] * kv[ki][2] + qv[qi][3] * kv[ki][3];
        }
#pragma unroll
        for (int qi = 0; qi < 4; ++qi)
#pragma unroll
            for (int ki = 0; ki < 4; ++ki) {
                int gq = q0 + t15 + 16 * qi, gk = k0 + tg + 16 * ki;
                float v = dacc[qi][ki];
                // sanitize: NaN/inf/garbage -> NEG_BIG (legit |logit| < 1e4)
                bool ok = (gk <= gq) && (fabsf(v) <= 1e8f);
                Ls[(t15 + 16 * qi) * 68 + tg + 16 * ki] = ok ? v : NEG_BIG;
            }
        __syncthreads();

        if (tid < 64) {
            const float* Lr = Ls + tid * 68;
            float mx = Ms[tid];
            for (int k = 0; k < 64; k += 4) {
                f32x4 v = *(const f32x4*)(Lr + k);
                mx = fmaxf(mx, fmaxf(fmaxf(v[0], v[1]), fmaxf(v[2], v[3])));
            }
            float s = 0.f;
            for (int k = 0; k < 64; k += 4) {
                f32x4 v = *(const f32x4*)(Lr + k);
                s += __expf(v[0] - mx) + __expf(v[1] - mx)
                   + __expf(v[2] - mx) + __expf(v[3] - mx);
            }
            float al = __expf(Ms[tid] - mx);
            As[tid] = al;
            Li[tid] = Li[tid] * al + s;
            Ms[tid] = mx;
        }
        __syncthreads();

        float al[4], mm[4];
#pragma unroll
        for (int qi = 0; qi < 4; ++qi) {
            al[qi] = As[t15 + 16 * qi];
            mm[qi] = Ms[t15 + 16 * qi];
        }
#pragma unroll
        for (int qi = 0; qi < 4; ++qi)
#pragma unroll
            for (int di = 0; di < 4; ++di) Oacc[qi][di] *= al[qi];
#pragma unroll
        for (int qi = 0; qi < 4; ++qi)
#pragma unroll
            for (int ki = 0; ki < 4; ++ki) {
                int idx = (t15 + 16 * qi) * 68 + tg + 16 * ki;
                Ls[idx] = __expf(Ls[idx] - mm[qi]);
            }
        __syncthreads();

        for (int k = 0; k < 64; ++k) {
            float pv[4];
#pragma unroll
            for (int qi = 0; qi < 4; ++qi)
                pv[qi] = Ls[(t15 + 16 * qi) * 68 + k];
#pragma unroll
            for (int di = 0; di < 4; ++di) {
                float vv = b2f(Vs[k * 72 + tg + 16 * di]);
#pragma unroll
                for (int qi = 0; qi < 4; ++qi) Oacc[qi][di] += pv[qi] * vv;
            }
        }
    }

#pragma unroll
    for (int qi = 0; qi < 4; ++qi) {
        float inv = 1.f / Li[t15 + 16 * qi];
        size_t orow = (size_t)(b * S_LEN + q0 + t15 + 16 * qi) * 1024 + h * 64;
#pragma unroll
        for (int di = 0; di < 4; ++di) {
            float o = Oacc[qi][di] * inv;
            o = (fabsf(o) <= 1e8f) ? o : 0.f;   // guarantee finite output
            outp[orow + tg + 16 * di] = f2b(o);
        }
    }
}

// ---------------------------------------------------------------------------
// y = proj + x0 ; LayerNorm over last dim (1024), no affine, eps=1e-5.
// Output dtype follows wire flag: fp32 or bf16.
// ---------------------------------------------------------------------------
__global__ __launch_bounds__(256) void ln_residual(
    const u16* __restrict__ proj, const u16* __restrict__ x0,
    void* __restrict__ out, const int* __restrict__ flag)
{
    __shared__ float red[8];
    __shared__ float stats[2];
    const size_t base = (size_t)blockIdx.x * 1024 + threadIdx.x * 4;
    union { uint2 u; u16 s[4]; } pa, xa;
    pa.u = *(const uint2*)(proj + base);
    xa.u = *(const uint2*)(x0 + base);
    float y[4];
    float s1 = 0.f, s2 = 0.f;
#pragma unroll
    for (int j = 0; j < 4; ++j) {
        y[j] = b2f(pa.s[j]) + b2f(xa.s[j]);
        if (!(fabsf(y[j]) <= 1e8f)) y[j] = 0.f;   // sanitize
        s1 += y[j];
        s2 += y[j] * y[j];
    }
#pragma unroll
    for (int off = 32; off > 0; off >>= 1) {
        s1 += __shfl_down(s1, off);
        s2 += __shfl_down(s2, off);
    }
    const int wave = threadIdx.x >> 6, lane = threadIdx.x & 63;
    if (lane == 0) { red[wave * 2] = s1; red[wave * 2 + 1] = s2; }
    __syncthreads();
    if (threadIdx.x == 0) {
        float S1 = red[0] + red[2] + red[4] + red[6];
        float S2 = red[1] + red[3] + red[5] + red[7];
        float mean = S1 * (1.f / 1024.f);
        float var  = fmaxf(S2 * (1.f / 1024.f) - mean * mean, 0.f);
        stats[0] = mean;
        stats[1] = rsqrtf(var + 1e-5f);
    }
    __syncthreads();
    float mean = stats[0], inv = stats[1];
    if (*flag) {
        f32x4 o;
#pragma unroll
        for (int j = 0; j < 4; ++j) o[j] = (y[j] - mean) * inv;
        *(f32x4*)((float*)out + base) = o;
    } else {
        union { uint2 u; u16 s[4]; } o;
#pragma unroll
        for (int j = 0; j < 4; ++j) o.s[j] = f2b((y[j] - mean) * inv);
        *(uint2*)((u16*)out + base) = o.u;
    }
}

// ---------------------------------------------------------------------------
extern "C" void kernel_launch(void* const* d_in, const int* in_sizes, int n_in,
                              void* d_out, int out_size, void* d_ws, size_t ws_size,
                              hipStream_t stream) {
    // d_in[3] = src_mask, all-False per spec -> ignored
    char* ws = (char*)d_ws;
    int* flag = (int*)ws;
    u16* cx0  = (u16*)(ws + 256);                 // 8192x1024 bf16
    u16* cwin = cx0  + (size_t)8192 * 1024;       // 1024x3072 bf16
    u16* cwo  = cwin + (size_t)1024 * 3072;       // 1024x1024 bf16
    u16* qkv  = cwo  + (size_t)1024 * 1024;       // 8192x3072 bf16
    u16* attn = qkv  + (size_t)8192 * 3072;       // 8192x1024 bf16
    u16* proj = qkv;                              // reuse qkv region (K3 after K2)

    dim3 blk(256);
    // P0: wire-dtype probe (fp32 vs bf16)
    probe_dtype<<<1, 64, 0, stream>>>((const u16*)d_in[0], flag);
    // P1: canonicalize inputs to bf16
    canon<<<4096, blk, 0, stream>>>(d_in[0], cx0,  8192 * 1024, flag);
    canon<<<1536, blk, 0, stream>>>(d_in[1], cwin, 1024 * 3072, flag);
    canon<<< 512, blk, 0, stream>>>(d_in[2], cwo,  1024 * 1024, flag);
    // K1: QKV projection
    gemm_bf16<<<dim3(64, 24), blk, 0, stream>>>(cx0, cwin, qkv, 8192, 3072, 1024);
    // K2: causal flash attention
    attn_fwd<<<dim3(32, 64), blk, 0, stream>>>(qkv, attn);
    // K3: output projection
    gemm_bf16<<<dim3(64, 8), blk, 0, stream>>>(attn, cwo, proj, 8192, 1024, 1024);
    // K4: residual + LayerNorm (output dtype per flag)
    ln_residual<<<dim3(8192), blk, 0, stream>>>(proj, cx0, d_out, flag);
}

// Round 4
// 544.844 us; speedup vs baseline: 5.6522x; 5.6522x over previous
//
#include <hip/hip_runtime.h>
#include <hip/hip_bf16.h>

typedef unsigned short u16;
typedef unsigned int u32;
typedef __attribute__((ext_vector_type(8))) short short8;  // bf16x8 MFMA A/B frag
typedef __attribute__((ext_vector_type(4))) float f32x4;   // MFMA acc / float4
typedef __attribute__((ext_vector_type(4))) int i32x4;     // 16B vector ld/st

__device__ __forceinline__ float b2f(u16 u) {
    union { u32 i; float f; } x; x.i = ((u32)u) << 16; return x.f;
}
__device__ __forceinline__ u16 f2b(float f) {
    union { float f; u32 u; } x; x.f = f;
    u32 r = x.u + 0x7fffu + ((x.u >> 16) & 1u);
    return (u16)(r >> 16);
}

// ---------------------------------------------------------------------------
// Dtype probe: flag = 1 (fp32 wire) / 0 (bf16 wire).
// ---------------------------------------------------------------------------
__global__ void probe_dtype(const u16* __restrict__ x, int* __restrict__ flag) {
    int bigf = 0;
    for (int i = threadIdx.x; i < 512; i += 64) {
        float v = fabsf(b2f(x[i]));
        if (!(v <= 1e6f)) bigf = 1;   // catches huge AND NaN
    }
    int any = __any(bigf);
    if (threadIdx.x == 0) *flag = any ? 1 : 0;
}

// ---------------------------------------------------------------------------
// Canonicalize input tensor to bf16: fp32 -> round; bf16 -> copy.
// ---------------------------------------------------------------------------
__global__ __launch_bounds__(256) void canon(
    const void* __restrict__ src, u16* __restrict__ dst, int n,
    const int* __restrict__ flag)
{
    int i = (blockIdx.x * 256 + threadIdx.x) * 8;
    if (i >= n) return;
    if (*flag) {
        const float* s = (const float*)src + i;
        f32x4 a = *(const f32x4*)s;
        f32x4 b = *(const f32x4*)(s + 4);
        union { i32x4 v; u16 h[8]; } o;
        o.h[0] = f2b(a[0]); o.h[1] = f2b(a[1]); o.h[2] = f2b(a[2]); o.h[3] = f2b(a[3]);
        o.h[4] = f2b(b[0]); o.h[5] = f2b(b[1]); o.h[6] = f2b(b[2]); o.h[7] = f2b(b[3]);
        *(i32x4*)(dst + i) = o.v;
    } else {
        *(i32x4*)(dst + i) = *(const i32x4*)((const u16*)src + i);
    }
}

// ---------------------------------------------------------------------------
// GEMM: C[M,N] = A[M,K] * B[K,N], bf16, fp32 accumulate. 128x128 tile, BK=32.
// (unchanged from round 3 — verified correct)
// ---------------------------------------------------------------------------
__global__ __launch_bounds__(256) void gemm_bf16(
    const u16* __restrict__ A, const u16* __restrict__ B, u16* __restrict__ C,
    int M, int N, int K)
{
    __shared__ __align__(16) u16 lA[128 * 32];   // [m][k], k-contiguous
    __shared__ __align__(16) u16 lB[128 * 40];   // [n][k] transposed, stride 40
    const int tid  = threadIdx.x;
    const int lane = tid & 63;
    const int wave = tid >> 6;
    const int la = lane & 15;
    const int qd = lane >> 4;
    const int m0 = blockIdx.x * 128, n0 = blockIdx.y * 128;
    const int wm = (wave & 1) * 64, wn = (wave >> 1) * 64;

    f32x4 acc[4][4];
    const f32x4 fz = {0.f, 0.f, 0.f, 0.f};
#pragma unroll
    for (int i = 0; i < 4; ++i)
#pragma unroll
        for (int j = 0; j < 4; ++j) acc[i][j] = fz;

    const int bn  = tid & 127;
    const int bkh = (tid >> 7) << 4;

    for (int k0 = 0; k0 < K; k0 += 32) {
        __syncthreads();
#pragma unroll
        for (int p = 0; p < 2; ++p) {
            int slot = tid + p * 256;
            int row = slot >> 2, seg = (slot & 3) << 3;
            *(i32x4*)(lA + row * 32 + seg) =
                *(const i32x4*)(A + (size_t)(m0 + row) * K + k0 + seg);
        }
        {
            const u16* gp = B + (size_t)(k0 + bkh) * N + n0 + bn;
            union { i32x4 v[2]; u16 s[16]; } t;
#pragma unroll
            for (int j = 0; j < 16; ++j) t.s[j] = gp[(size_t)j * N];
            *(i32x4*)(lB + bn * 40 + bkh)     = t.v[0];
            *(i32x4*)(lB + bn * 40 + bkh + 8) = t.v[1];
        }
        __syncthreads();

        short8 af[4], bf[4];
#pragma unroll
        for (int i = 0; i < 4; ++i)
            af[i] = *(const short8*)(lA + (wm + i * 16 + la) * 32 + qd * 8);
#pragma unroll
        for (int j = 0; j < 4; ++j)
            bf[j] = *(const short8*)(lB + (wn + j * 16 + la) * 40 + qd * 8);
#pragma unroll
        for (int i = 0; i < 4; ++i)
#pragma unroll
            for (int j = 0; j < 4; ++j)
                acc[i][j] = __builtin_amdgcn_mfma_f32_16x16x32_bf16(
                    af[i], bf[j], acc[i][j], 0, 0, 0);
    }

#pragma unroll
    for (int i = 0; i < 4; ++i)
#pragma unroll
        for (int j = 0; j < 4; ++j)
#pragma unroll
            for (int r = 0; r < 4; ++r) {
                int row = m0 + wm + i * 16 + qd * 4 + r;
                int col = n0 + wn + j * 16 + la;
                C[(size_t)row * N + col] = f2b(acc[i][j][r]);
            }
}

// ---------------------------------------------------------------------------
// MFMA flash attention. Block = 256 threads = 4 waves, one (b,h), 64 q-rows.
// Wave w owns q-rows [w*16, w*16+16). Per kt-tile:
//   QK^T: 8 MFMAs/wave (4 n-tiles x 2 k-steps), D-layout regs
//   softmax: in-register, row stats via __shfl_xor within 16-lane quad group
//   P (bf16) -> LDS (D-layout -> A-layout transform), V transpose-staged
//   PV: 8 MFMAs/wave into O accumulator (same row ownership as softmax)
// LDS stride 72 u16 = 144 B: 16B-aligned for ds_read_b128, 2-way bank alias.
// ---------------------------------------------------------------------------
#define S_LEN 2048
#define D3 3072
#define NEG_BIG (-30000.0f)

__global__ __launch_bounds__(256, 4) void attn_fwd(
    const u16* __restrict__ qkv, u16* __restrict__ outp)
{
    __shared__ __align__(16) u16 Qs[64 * 72];   // [q][d]
    __shared__ __align__(16) u16 Ks[64 * 72];   // [kcol][d]
    __shared__ __align__(16) u16 Vt[64 * 72];   // [d][kcol]  (transposed)
    __shared__ __align__(16) u16 Ps[64 * 72];   // [q][kcol]
    const int tid  = threadIdx.x;
    const int lane = tid & 63;
    const int wave = tid >> 6;
    const int la = lane & 15;      // frag row (A) / col (B,D)
    const int qd = lane >> 4;      // quad
    const int qt = 31 - blockIdx.x;     // big tiles first
    const int bh = blockIdx.y;
    const int b = bh >> 4, h = bh & 15;
    const int q0 = qt * 64;
    const size_t rowb = (size_t)b * S_LEN * D3;
    const int hq = h * 192;

    // stage Q once (raw bf16)
#pragma unroll
    for (int p = 0; p < 2; ++p) {
        int slot = tid + p * 256;
        int row = slot >> 3, seg = (slot & 7) << 3;
        *(i32x4*)(Qs + row * 72 + seg) =
            *(const i32x4*)(qkv + rowb + (size_t)(q0 + row) * D3 + hq + seg);
    }

    f32x4 Oacc[4];                 // [jd]: O[wave*16 + qd*4+r][jd*16+la]
    const f32x4 fz = {0.f, 0.f, 0.f, 0.f};
#pragma unroll
    for (int jd = 0; jd < 4; ++jd) Oacc[jd] = fz;
    float m_i[4], l_i[4];
#pragma unroll
    for (int r = 0; r < 4; ++r) { m_i[r] = NEG_BIG; l_i[r] = 0.f; }

    for (int kt = 0; kt <= qt; ++kt) {
        const int k0 = kt * 64;
        __syncthreads();   // prev PV reads of Ps/Vt/Ks done; covers Q stage at kt=0
        // stage K [kcol][d]
#pragma unroll
        for (int p = 0; p < 2; ++p) {
            int slot = tid + p * 256;
            int row = slot >> 3, seg = (slot & 7) << 3;
            *(i32x4*)(Ks + row * 72 + seg) =
                *(const i32x4*)(qkv + rowb + (size_t)(k0 + row) * D3 + hq + 64 + seg);
        }
        // stage V transposed -> Vt[d][kcol]
#pragma unroll
        for (int p = 0; p < 2; ++p) {
            int slot = tid + p * 256;
            int kc = slot >> 3, d0 = (slot & 7) << 3;
            union { i32x4 v; u16 s[8]; } u;
            u.v = *(const i32x4*)(qkv + rowb + (size_t)(k0 + kc) * D3 + hq + 128 + d0);
#pragma unroll
            for (int j = 0; j < 8; ++j) Vt[(d0 + j) * 72 + kc] = u.s[j];
        }
        __syncthreads();

        // ---- QK^T ----
        f32x4 sacc[4];
#pragma unroll
        for (int jn = 0; jn < 4; ++jn) sacc[jn] = fz;
#pragma unroll
        for (int s = 0; s < 2; ++s) {
            short8 af = *(const short8*)(Qs + (wave * 16 + la) * 72 + s * 32 + qd * 8);
#pragma unroll
            for (int jn = 0; jn < 4; ++jn) {
                short8 bf = *(const short8*)(Ks + (jn * 16 + la) * 72 + s * 32 + qd * 8);
                sacc[jn] = __builtin_amdgcn_mfma_f32_16x16x32_bf16(af, bf, sacc[jn], 0, 0, 0);
            }
        }
        // scale; causal mask only on the diagonal tile
#pragma unroll
        for (int jn = 0; jn < 4; ++jn)
#pragma unroll
            for (int r = 0; r < 4; ++r) sacc[jn][r] *= 0.125f;
        if (kt == qt) {
#pragma unroll
            for (int jn = 0; jn < 4; ++jn)
#pragma unroll
                for (int r = 0; r < 4; ++r)
                    if (jn * 16 + la > wave * 16 + qd * 4 + r) sacc[jn][r] = NEG_BIG;
        }

        // ---- row stats (within 16-lane quad group) ----
        float mnew[4], al[4], rs[4];
#pragma unroll
        for (int r = 0; r < 4; ++r) {
            float t = fmaxf(fmaxf(sacc[0][r], sacc[1][r]), fmaxf(sacc[2][r], sacc[3][r]));
            t = fmaxf(t, __shfl_xor(t, 1));
            t = fmaxf(t, __shfl_xor(t, 2));
            t = fmaxf(t, __shfl_xor(t, 4));
            t = fmaxf(t, __shfl_xor(t, 8));
            mnew[r] = fmaxf(m_i[r], t);
            al[r]   = __expf(m_i[r] - mnew[r]);   // first tile: underflows to 0
            rs[r]   = 0.f;
        }
        // ---- P = exp(S - m), write bf16 to Ps, accumulate row sums ----
#pragma unroll
        for (int jn = 0; jn < 4; ++jn)
#pragma unroll
            for (int r = 0; r < 4; ++r) {
                float pv = __expf(sacc[jn][r] - mnew[r]);
                rs[r] += pv;
                Ps[(wave * 16 + qd * 4 + r) * 72 + jn * 16 + la] = f2b(pv);
            }
#pragma unroll
        for (int r = 0; r < 4; ++r) {
            float s = rs[r];
            s += __shfl_xor(s, 1);
            s += __shfl_xor(s, 2);
            s += __shfl_xor(s, 4);
            s += __shfl_xor(s, 8);
            l_i[r] = l_i[r] * al[r] + s;
            m_i[r] = mnew[r];
        }
        // rescale O
#pragma unroll
        for (int jd = 0; jd < 4; ++jd)
#pragma unroll
            for (int r = 0; r < 4; ++r) Oacc[jd][r] *= al[r];
        __syncthreads();   // Ps visible to all; Ks/Qs reads done

        // ---- PV ----
#pragma unroll
        for (int s = 0; s < 2; ++s) {
            short8 af = *(const short8*)(Ps + (wave * 16 + la) * 72 + s * 32 + qd * 8);
#pragma unroll
            for (int jd = 0; jd < 4; ++jd) {
                short8 bf = *(const short8*)(Vt + (jd * 16 + la) * 72 + s * 32 + qd * 8);
                Oacc[jd] = __builtin_amdgcn_mfma_f32_16x16x32_bf16(af, bf, Oacc[jd], 0, 0, 0);
            }
        }
    }

    // epilogue: out[b, q0 + wave*16 + qd*4 + r, h*64 + jd*16 + la]
#pragma unroll
    for (int r = 0; r < 4; ++r) {
        float inv = 1.f / l_i[r];
        size_t orow = (size_t)(b * S_LEN + q0 + wave * 16 + qd * 4 + r) * 1024 + h * 64;
#pragma unroll
        for (int jd = 0; jd < 4; ++jd)
            outp[orow + jd * 16 + la] = f2b(Oacc[jd][r] * inv);
    }
}

// ---------------------------------------------------------------------------
// y = proj + x0 ; LayerNorm over last dim (1024). Output dtype per wire flag.
// ---------------------------------------------------------------------------
__global__ __launch_bounds__(256) void ln_residual(
    const u16* __restrict__ proj, const u16* __restrict__ x0,
    void* __restrict__ out, const int* __restrict__ flag)
{
    __shared__ float red[8];
    __shared__ float stats[2];
    const size_t base = (size_t)blockIdx.x * 1024 + threadIdx.x * 4;
    union { uint2 u; u16 s[4]; } pa, xa;
    pa.u = *(const uint2*)(proj + base);
    xa.u = *(const uint2*)(x0 + base);
    float y[4];
    float s1 = 0.f, s2 = 0.f;
#pragma unroll
    for (int j = 0; j < 4; ++j) {
        y[j] = b2f(pa.s[j]) + b2f(xa.s[j]);
        s1 += y[j];
        s2 += y[j] * y[j];
    }
#pragma unroll
    for (int off = 32; off > 0; off >>= 1) {
        s1 += __shfl_down(s1, off);
        s2 += __shfl_down(s2, off);
    }
    const int wave = threadIdx.x >> 6, lane = threadIdx.x & 63;
    if (lane == 0) { red[wave * 2] = s1; red[wave * 2 + 1] = s2; }
    __syncthreads();
    if (threadIdx.x == 0) {
        float S1 = red[0] + red[2] + red[4] + red[6];
        float S2 = red[1] + red[3] + red[5] + red[7];
        float mean = S1 * (1.f / 1024.f);
        float var  = fmaxf(S2 * (1.f / 1024.f) - mean * mean, 0.f);
        stats[0] = mean;
        stats[1] = rsqrtf(var + 1e-5f);
    }
    __syncthreads();
    float mean = stats[0], inv = stats[1];
    if (*flag) {
        f32x4 o;
#pragma unroll
        for (int j = 0; j < 4; ++j) o[j] = (y[j] - mean) * inv;
        *(f32x4*)((float*)out + base) = o;
    } else {
        union { uint2 u; u16 s[4]; } o;
#pragma unroll
        for (int j = 0; j < 4; ++j) o.s[j] = f2b((y[j] - mean) * inv);
        *(uint2*)((u16*)out + base) = o.u;
    }
}

// ---------------------------------------------------------------------------
extern "C" void kernel_launch(void* const* d_in, const int* in_sizes, int n_in,
                              void* d_out, int out_size, void* d_ws, size_t ws_size,
                              hipStream_t stream) {
    // d_in[3] = src_mask, all-False per spec -> ignored
    char* ws = (char*)d_ws;
    int* flag = (int*)ws;
    u16* cx0  = (u16*)(ws + 256);                 // 8192x1024 bf16
    u16* cwin = cx0  + (size_t)8192 * 1024;       // 1024x3072 bf16
    u16* cwo  = cwin + (size_t)1024 * 3072;       // 1024x1024 bf16
    u16* qkv  = cwo  + (size_t)1024 * 1024;       // 8192x3072 bf16
    u16* attn = qkv  + (size_t)8192 * 3072;       // 8192x1024 bf16
    u16* proj = qkv;                              // reuse qkv region (K3 after K2)

    dim3 blk(256);
    probe_dtype<<<1, 64, 0, stream>>>((const u16*)d_in[0], flag);
    canon<<<4096, blk, 0, stream>>>(d_in[0], cx0,  8192 * 1024, flag);
    canon<<<1536, blk, 0, stream>>>(d_in[1], cwin, 1024 * 3072, flag);
    canon<<< 512, blk, 0, stream>>>(d_in[2], cwo,  1024 * 1024, flag);
    gemm_bf16<<<dim3(64, 24), blk, 0, stream>>>(cx0, cwin, qkv, 8192, 3072, 1024);
    attn_fwd<<<dim3(32, 64), blk, 0, stream>>>(qkv, attn);
    gemm_bf16<<<dim3(64, 8), blk, 0, stream>>>(attn, cwo, proj, 8192, 1024, 1024);
    ln_residual<<<dim3(8192), blk, 0, stream>>>(proj, cx0, d_out, flag);
}

// Round 5
// 383.438 us; speedup vs baseline: 8.0315x; 1.4209x over previous
//
#include <hip/hip_runtime.h>
#include <hip/hip_bf16.h>

typedef unsigned short u16;
typedef unsigned int u32;
typedef __attribute__((ext_vector_type(8))) short short8;  // bf16x8 MFMA A/B frag
typedef __attribute__((ext_vector_type(4))) float f32x4;   // MFMA acc / float4
typedef __attribute__((ext_vector_type(4))) int i32x4;     // 16B vector ld/st

__device__ __forceinline__ float b2f(u16 u) {
    union { u32 i; float f; } x; x.i = ((u32)u) << 16; return x.f;
}
__device__ __forceinline__ u16 f2b(float f) {
    union { float f; u32 u; } x; x.f = f;
    u32 r = x.u + 0x7fffu + ((x.u >> 16) & 1u);
    return (u16)(r >> 16);
}

// ---------------------------------------------------------------------------
// Dtype probe: flag = 1 (fp32 wire) / 0 (bf16 wire).
// ---------------------------------------------------------------------------
__global__ void probe_dtype(const u16* __restrict__ x, int* __restrict__ flag) {
    int bigf = 0;
    for (int i = threadIdx.x; i < 512; i += 64) {
        float v = fabsf(b2f(x[i]));
        if (!(v <= 1e6f)) bigf = 1;
    }
    int any = __any(bigf);
    if (threadIdx.x == 0) *flag = any ? 1 : 0;
}

// ---------------------------------------------------------------------------
// Canonicalize to bf16 (no transpose): fp32 -> round; bf16 -> copy.
// ---------------------------------------------------------------------------
__global__ __launch_bounds__(256) void canon(
    const void* __restrict__ src, u16* __restrict__ dst, int n,
    const int* __restrict__ flag)
{
    int i = (blockIdx.x * 256 + threadIdx.x) * 8;
    if (i >= n) return;
    if (*flag) {
        const float* s = (const float*)src + i;
        f32x4 a = *(const f32x4*)s;
        f32x4 b = *(const f32x4*)(s + 4);
        union { i32x4 v; u16 h[8]; } o;
        o.h[0] = f2b(a[0]); o.h[1] = f2b(a[1]); o.h[2] = f2b(a[2]); o.h[3] = f2b(a[3]);
        o.h[4] = f2b(b[0]); o.h[5] = f2b(b[1]); o.h[6] = f2b(b[2]); o.h[7] = f2b(b[3]);
        *(i32x4*)(dst + i) = o.v;
    } else {
        *(i32x4*)(dst + i) = *(const i32x4*)((const u16*)src + i);
    }
}

// ---------------------------------------------------------------------------
// Fused canonicalize + transpose: src [M][N] (fp32/bf16) -> dst [N][M] bf16.
// 64x64 LDS tile. Grid (M/64, N/64).
// ---------------------------------------------------------------------------
__global__ __launch_bounds__(256) void canon_t(
    const void* __restrict__ src, u16* __restrict__ dst, int Mdim, int Ndim,
    const int* __restrict__ flag)
{
    __shared__ __align__(16) u16 t[64 * 72];
    const int m0 = blockIdx.x * 64, n0 = blockIdx.y * 64;
    const int tid = threadIdx.x;
    const bool f = (*flag != 0);
#pragma unroll
    for (int p = 0; p < 2; ++p) {
        int s = tid + p * 256;
        int r = s >> 3, c0 = (s & 7) << 3;
        union { i32x4 v; u16 h[8]; } o;
        if (f) {
            const float* sp = (const float*)src + (size_t)(m0 + r) * Ndim + n0 + c0;
            f32x4 a = *(const f32x4*)sp, b = *(const f32x4*)(sp + 4);
            o.h[0] = f2b(a[0]); o.h[1] = f2b(a[1]); o.h[2] = f2b(a[2]); o.h[3] = f2b(a[3]);
            o.h[4] = f2b(b[0]); o.h[5] = f2b(b[1]); o.h[6] = f2b(b[2]); o.h[7] = f2b(b[3]);
        } else {
            o.v = *(const i32x4*)((const u16*)src + (size_t)(m0 + r) * Ndim + n0 + c0);
        }
        *(i32x4*)(t + r * 72 + c0) = o.v;
    }
    __syncthreads();
#pragma unroll
    for (int p = 0; p < 2; ++p) {
        int s = tid + p * 256;
        int oc = s >> 3, mc = (s & 7) << 3;
        union { i32x4 v; u16 h[8]; } o;
#pragma unroll
        for (int j = 0; j < 8; ++j) o.h[j] = t[(mc + j) * 72 + oc];
        *(i32x4*)(dst + (size_t)(n0 + oc) * Mdim + m0 + mc) = o.v;
    }
}

// ---------------------------------------------------------------------------
// V pre-transpose: qkv[b][s][h*192+128+d] -> vT[h*64+d][b*2048+s].
// Grid (64 bh, 32 s-tiles).
// ---------------------------------------------------------------------------
__global__ __launch_bounds__(256) void vtrans(
    const u16* __restrict__ qkv, u16* __restrict__ vT)
{
    __shared__ __align__(16) u16 t[64 * 72];
    const int bh = blockIdx.x, b = bh >> 4, h = bh & 15;
    const int s0 = blockIdx.y * 64;
    const int tid = threadIdx.x;
#pragma unroll
    for (int p = 0; p < 2; ++p) {
        int s = tid + p * 256;
        int r = s >> 3, c0 = (s & 7) << 3;
        *(i32x4*)(t + r * 72 + c0) =
            *(const i32x4*)(qkv + (size_t)(b * 2048 + s0 + r) * 3072 + h * 192 + 128 + c0);
    }
    __syncthreads();
#pragma unroll
    for (int p = 0; p < 2; ++p) {
        int s = tid + p * 256;
        int oc = s >> 3, mc = (s & 7) << 3;   // oc = d, mc = s-chunk
        union { i32x4 v; u16 h[8]; } o;
#pragma unroll
        for (int j = 0; j < 8; ++j) o.h[j] = t[(mc + j) * 72 + oc];
        *(i32x4*)(vT + (size_t)(h * 64 + oc) * 8192 + b * 2048 + s0 + mc) = o.v;
    }
}

// ---------------------------------------------------------------------------
// GEMM: C[M,N] = A[M,K] * Bt[N,K]^T, bf16, fp32 acc. 128x128 tile, BK=32.
// Both operands k-contiguous -> all staging is 16B vector loads.
// ---------------------------------------------------------------------------
__global__ __launch_bounds__(256) void gemm_bf16(
    const u16* __restrict__ A, const u16* __restrict__ Bt, u16* __restrict__ C,
    int M, int N, int K)
{
    __shared__ __align__(16) u16 lA[128 * 32];   // [m][k]
    __shared__ __align__(16) u16 lB[128 * 40];   // [n][k], stride 40
    const int tid  = threadIdx.x;
    const int lane = tid & 63;
    const int wave = tid >> 6;
    const int la = lane & 15;
    const int qd = lane >> 4;
    const int m0 = blockIdx.x * 128, n0 = blockIdx.y * 128;
    const int wm = (wave & 1) * 64, wn = (wave >> 1) * 64;

    f32x4 acc[4][4];
    const f32x4 fz = {0.f, 0.f, 0.f, 0.f};
#pragma unroll
    for (int i = 0; i < 4; ++i)
#pragma unroll
        for (int j = 0; j < 4; ++j) acc[i][j] = fz;

    for (int k0 = 0; k0 < K; k0 += 32) {
        __syncthreads();
#pragma unroll
        for (int p = 0; p < 2; ++p) {
            int slot = tid + p * 256;
            int row = slot >> 2, seg = (slot & 3) << 3;
            *(i32x4*)(lA + row * 32 + seg) =
                *(const i32x4*)(A + (size_t)(m0 + row) * K + k0 + seg);
            *(i32x4*)(lB + row * 40 + seg) =
                *(const i32x4*)(Bt + (size_t)(n0 + row) * K + k0 + seg);
        }
        __syncthreads();

        short8 af[4], bf[4];
#pragma unroll
        for (int i = 0; i < 4; ++i)
            af[i] = *(const short8*)(lA + (wm + i * 16 + la) * 32 + qd * 8);
#pragma unroll
        for (int j = 0; j < 4; ++j)
            bf[j] = *(const short8*)(lB + (wn + j * 16 + la) * 40 + qd * 8);
#pragma unroll
        for (int i = 0; i < 4; ++i)
#pragma unroll
            for (int j = 0; j < 4; ++j)
                acc[i][j] = __builtin_amdgcn_mfma_f32_16x16x32_bf16(
                    af[i], bf[j], acc[i][j], 0, 0, 0);
    }

#pragma unroll
    for (int i = 0; i < 4; ++i)
#pragma unroll
        for (int j = 0; j < 4; ++j)
#pragma unroll
            for (int r = 0; r < 4; ++r) {
                int row = m0 + wm + i * 16 + qd * 4 + r;
                int col = n0 + wn + j * 16 + la;
                C[(size_t)row * N + col] = f2b(acc[i][j][r]);
            }
}

// ---------------------------------------------------------------------------
// MFMA flash attention v2. Block = 4 waves, one (b,h), 64 q-rows (16/wave).
// S^T trick: QK^T computed as K·Q^T (A=K, B=Q) so D-layout gives q = la ->
// each lane owns ONE q-row; softmax row stats = in-reg reduce + 2 shuffles.
// P is wave-private in LDS (b64 packed writes). V pre-transposed globally.
// K/V staged with register prefetch; 2 barriers per tile.
// ---------------------------------------------------------------------------
#define S_LEN 2048
#define D3 3072
#define NEG_BIG (-30000.0f)

__global__ __launch_bounds__(256) void attn_fwd(
    const u16* __restrict__ qkv, const u16* __restrict__ vT,
    u16* __restrict__ outp)
{
    __shared__ __align__(16) u16 Qs[64 * 72];   // [q][d]
    __shared__ __align__(16) u16 Ks[64 * 72];   // [kcol][d]
    __shared__ __align__(16) u16 Vts[64 * 72];  // [d][kcol]
    __shared__ __align__(16) u16 Ps[64 * 72];   // [q][kcol]  (wave-private rows)
    const int tid  = threadIdx.x;
    const int lane = tid & 63;
    const int wave = tid >> 6;
    const int la = lane & 15;
    const int qd = lane >> 4;
    const int qt = 31 - blockIdx.x;     // big tiles first
    const int bh = blockIdx.y;
    const int b = bh >> 4, h = bh & 15;
    const int q0 = qt * 64;
    const size_t rowb = (size_t)b * S_LEN * D3;
    const int hq = h * 192;
    const u16* vTp = vT + (size_t)(h * 64) * 8192 + b * 2048;

    // stage Q once
#pragma unroll
    for (int p = 0; p < 2; ++p) {
        int slot = tid + p * 256;
        int row = slot >> 3, seg = (slot & 7) << 3;
        *(i32x4*)(Qs + row * 72 + seg) =
            *(const i32x4*)(qkv + rowb + (size_t)(q0 + row) * D3 + hq + seg);
    }

    f32x4 Oacc[4];                     // [jd]: O[q=qd*4+r][d=jd*16+la]
    const f32x4 fz = {0.f, 0.f, 0.f, 0.f};
#pragma unroll
    for (int jd = 0; jd < 4; ++jd) Oacc[jd] = fz;
    float m_run = NEG_BIG, l_run = 0.f;   // state for q = q0 + wave*16 + la

    // prefetch tile 0
    i32x4 kreg[2], vreg[2];
    {
#pragma unroll
        for (int p = 0; p < 2; ++p) {
            int slot = tid + p * 256;
            int row = slot >> 3, seg = (slot & 7) << 3;
            kreg[p] = *(const i32x4*)(qkv + rowb + (size_t)row * D3 + hq + 64 + seg);
            vreg[p] = *(const i32x4*)(vTp + (size_t)row * 8192 + seg);
        }
    }

    for (int kt = 0; kt <= qt; ++kt) {
        __syncthreads();   // prev-iter LDS reads done (covers Q stage at kt=0)
#pragma unroll
        for (int p = 0; p < 2; ++p) {
            int slot = tid + p * 256;
            int row = slot >> 3, seg = (slot & 7) << 3;
            *(i32x4*)(Ks  + row * 72 + seg) = kreg[p];
            *(i32x4*)(Vts + row * 72 + seg) = vreg[p];
        }
        if (kt < qt) {
            const int kn = (kt + 1) * 64;
#pragma unroll
            for (int p = 0; p < 2; ++p) {
                int slot = tid + p * 256;
                int row = slot >> 3, seg = (slot & 7) << 3;
                kreg[p] = *(const i32x4*)(qkv + rowb + (size_t)(kn + row) * D3 + hq + 64 + seg);
                vreg[p] = *(const i32x4*)(vTp + (size_t)row * 8192 + kn + seg);
            }
        }
        __syncthreads();   // staging visible

        // ---- S^T = K . Q^T : sacc[jm][r] = S[q=la][kc=jm*16+qd*4+r] ----
        f32x4 sacc[4];
#pragma unroll
        for (int jm = 0; jm < 4; ++jm) sacc[jm] = fz;
#pragma unroll
        for (int s = 0; s < 2; ++s) {
            short8 bq = *(const short8*)(Qs + (wave * 16 + la) * 72 + s * 32 + qd * 8);
#pragma unroll
            for (int jm = 0; jm < 4; ++jm) {
                short8 ak = *(const short8*)(Ks + (jm * 16 + la) * 72 + s * 32 + qd * 8);
                sacc[jm] = __builtin_amdgcn_mfma_f32_16x16x32_bf16(ak, bq, sacc[jm], 0, 0, 0);
            }
        }
#pragma unroll
        for (int jm = 0; jm < 4; ++jm)
#pragma unroll
            for (int r = 0; r < 4; ++r) sacc[jm][r] *= 0.125f;
        if (kt == qt) {   // causal mask on diagonal tile
#pragma unroll
            for (int jm = 0; jm < 4; ++jm)
#pragma unroll
                for (int r = 0; r < 4; ++r)
                    if (jm * 16 + qd * 4 + r > wave * 16 + la) sacc[jm][r] = NEG_BIG;
        }

        // ---- row stats: in-reg reduce over 16 elems, 2 shuffles over qd ----
        float mx = fmaxf(fmaxf(fmaxf(sacc[0][0], sacc[0][1]), fmaxf(sacc[0][2], sacc[0][3])),
                         fmaxf(fmaxf(sacc[1][0], sacc[1][1]), fmaxf(sacc[1][2], sacc[1][3])));
        mx = fmaxf(mx, fmaxf(fmaxf(fmaxf(sacc[2][0], sacc[2][1]), fmaxf(sacc[2][2], sacc[2][3])),
                             fmaxf(fmaxf(sacc[3][0], sacc[3][1]), fmaxf(sacc[3][2], sacc[3][3]))));
        mx = fmaxf(mx, __shfl_xor(mx, 16));
        mx = fmaxf(mx, __shfl_xor(mx, 32));
        float mnew = fmaxf(m_run, mx);
        float al   = __expf(m_run - mnew);   // first tile: underflows to 0
        float ssum = 0.f;
#pragma unroll
        for (int jm = 0; jm < 4; ++jm)
#pragma unroll
            for (int r = 0; r < 4; ++r) {
                float pv = __expf(sacc[jm][r] - mnew);
                sacc[jm][r] = pv;
                ssum += pv;
            }
        ssum += __shfl_xor(ssum, 16);
        ssum += __shfl_xor(ssum, 32);
        l_run = l_run * al + ssum;
        m_run = mnew;

        // ---- P -> LDS (packed b64, wave-private rows) ----
#pragma unroll
        for (int jm = 0; jm < 4; ++jm) {
            union { uint2 u; u16 h[4]; } w;
#pragma unroll
            for (int r = 0; r < 4; ++r) w.h[r] = f2b(sacc[jm][r]);
            *(uint2*)(Ps + (wave * 16 + la) * 72 + jm * 16 + qd * 4) = w.u;
        }

        // ---- O rescale: alpha for O-rows qd*4+r lives in lane qd*4+r ----
        float ar[4];
#pragma unroll
        for (int r = 0; r < 4; ++r) ar[r] = __shfl(al, qd * 4 + r);
#pragma unroll
        for (int jd = 0; jd < 4; ++jd)
#pragma unroll
            for (int r = 0; r < 4; ++r) Oacc[jd][r] *= ar[r];

        // ---- PV: A = Ps (own wave rows), B = Vts ----
#pragma unroll
        for (int s = 0; s < 2; ++s) {
            short8 ap = *(const short8*)(Ps + (wave * 16 + la) * 72 + s * 32 + qd * 8);
#pragma unroll
            for (int jd = 0; jd < 4; ++jd) {
                short8 bv = *(const short8*)(Vts + (jd * 16 + la) * 72 + s * 32 + qd * 8);
                Oacc[jd] = __builtin_amdgcn_mfma_f32_16x16x32_bf16(ap, bv, Oacc[jd], 0, 0, 0);
            }
        }
    }

    // epilogue: O row q = q0 + wave*16 + qd*4 + r, col h*64 + jd*16 + la
#pragma unroll
    for (int r = 0; r < 4; ++r) {
        float lr = __shfl(l_run, qd * 4 + r);
        float inv = 1.f / lr;
        size_t orow = (size_t)(b * S_LEN + q0 + wave * 16 + qd * 4 + r) * 1024 + h * 64;
#pragma unroll
        for (int jd = 0; jd < 4; ++jd)
            outp[orow + jd * 16 + la] = f2b(Oacc[jd][r] * inv);
    }
}

// ---------------------------------------------------------------------------
// y = proj + x0 ; LayerNorm over last dim (1024). Output dtype per wire flag.
// ---------------------------------------------------------------------------
__global__ __launch_bounds__(256) void ln_residual(
    const u16* __restrict__ proj, const u16* __restrict__ x0,
    void* __restrict__ out, const int* __restrict__ flag)
{
    __shared__ float red[8];
    __shared__ float stats[2];
    const size_t base = (size_t)blockIdx.x * 1024 + threadIdx.x * 4;
    union { uint2 u; u16 s[4]; } pa, xa;
    pa.u = *(const uint2*)(proj + base);
    xa.u = *(const uint2*)(x0 + base);
    float y[4];
    float s1 = 0.f, s2 = 0.f;
#pragma unroll
    for (int j = 0; j < 4; ++j) {
        y[j] = b2f(pa.s[j]) + b2f(xa.s[j]);
        s1 += y[j];
        s2 += y[j] * y[j];
    }
#pragma unroll
    for (int off = 32; off > 0; off >>= 1) {
        s1 += __shfl_down(s1, off);
        s2 += __shfl_down(s2, off);
    }
    const int wave = threadIdx.x >> 6, lane = threadIdx.x & 63;
    if (lane == 0) { red[wave * 2] = s1; red[wave * 2 + 1] = s2; }
    __syncthreads();
    if (threadIdx.x == 0) {
        float S1 = red[0] + red[2] + red[4] + red[6];
        float S2 = red[1] + red[3] + red[5] + red[7];
        float mean = S1 * (1.f / 1024.f);
        float var  = fmaxf(S2 * (1.f / 1024.f) - mean * mean, 0.f);
        stats[0] = mean;
        stats[1] = rsqrtf(var + 1e-5f);
    }
    __syncthreads();
    float mean = stats[0], inv = stats[1];
    if (*flag) {
        f32x4 o;
#pragma unroll
        for (int j = 0; j < 4; ++j) o[j] = (y[j] - mean) * inv;
        *(f32x4*)((float*)out + base) = o;
    } else {
        union { uint2 u; u16 s[4]; } o;
#pragma unroll
        for (int j = 0; j < 4; ++j) o.s[j] = f2b((y[j] - mean) * inv);
        *(uint2*)((u16*)out + base) = o.u;
    }
}

// ---------------------------------------------------------------------------
extern "C" void kernel_launch(void* const* d_in, const int* in_sizes, int n_in,
                              void* d_out, int out_size, void* d_ws, size_t ws_size,
                              hipStream_t stream) {
    // d_in[3] = src_mask, all-False per spec -> ignored
    char* ws = (char*)d_ws;
    int* flag = (int*)ws;
    u16* cx0  = (u16*)(ws + 256);                 // 8192x1024  bf16 (16 MB)
    u16* wtin = cx0  + (size_t)8192 * 1024;       // W_in^T [3072][1024] (6 MB)
    u16* wto  = wtin + (size_t)3072 * 1024;       // W_o^T  [1024][1024] (2 MB)
    u16* qkv  = wto  + (size_t)1024 * 1024;       // 8192x3072 (48 MB)
    u16* vT   = qkv  + (size_t)8192 * 3072;       // [16*64][8192] (16 MB)
    u16* attn = vT   + (size_t)1024 * 8192;       // 8192x1024 (16 MB)
    u16* proj = qkv;                              // reuse qkv region (K3 after K2)

    dim3 blk(256);
    probe_dtype<<<1, 64, 0, stream>>>((const u16*)d_in[0], flag);
    canon<<<4096, blk, 0, stream>>>(d_in[0], cx0, 8192 * 1024, flag);
    canon_t<<<dim3(16, 48), blk, 0, stream>>>(d_in[1], wtin, 1024, 3072, flag);
    canon_t<<<dim3(16, 16), blk, 0, stream>>>(d_in[2], wto,  1024, 1024, flag);
    // K1: QKV projection (B pre-transposed)
    gemm_bf16<<<dim3(64, 24), blk, 0, stream>>>(cx0, wtin, qkv, 8192, 3072, 1024);
    // V pre-transpose
    vtrans<<<dim3(64, 32), blk, 0, stream>>>(qkv, vT);
    // K2: causal flash attention
    attn_fwd<<<dim3(32, 64), blk, 0, stream>>>(qkv, vT, attn);
    // K3: output projection
    gemm_bf16<<<dim3(64, 8), blk, 0, stream>>>(attn, wto, proj, 8192, 1024, 1024);
    // K4: residual + LayerNorm
    ln_residual<<<dim3(8192), blk, 0, stream>>>(proj, cx0, d_out, flag);
}

// Round 6
// 372.187 us; speedup vs baseline: 8.2743x; 1.0302x over previous
//
#include <hip/hip_runtime.h>
#include <hip/hip_bf16.h>

typedef unsigned short u16;
typedef unsigned int u32;
typedef __attribute__((ext_vector_type(8))) short short8;  // bf16x8 MFMA A/B frag
typedef __attribute__((ext_vector_type(4))) float f32x4;   // MFMA acc / float4
typedef __attribute__((ext_vector_type(4))) int i32x4;     // 16B vector ld/st

__device__ __forceinline__ float b2f(u16 u) {
    union { u32 i; float f; } x; x.i = ((u32)u) << 16; return x.f;
}
__device__ __forceinline__ u16 f2b(float f) {
    union { float f; u32 u; } x; x.f = f;
    u32 r = x.u + 0x7fffu + ((x.u >> 16) & 1u);
    return (u16)(r >> 16);
}
// async 16B global->LDS (wave-uniform LDS base + lane*16; m97 pattern)
__device__ __forceinline__ void async_cp16(const u16* g, u16* l) {
    __builtin_amdgcn_global_load_lds(
        (const __attribute__((address_space(1))) void*)g,
        (__attribute__((address_space(3))) void*)l, 16, 0, 0);
}

// ---------------------------------------------------------------------------
// Dtype probe: flag = 1 (fp32 wire) / 0 (bf16 wire).
// ---------------------------------------------------------------------------
__global__ void probe_dtype(const u16* __restrict__ x, int* __restrict__ flag) {
    int bigf = 0;
    for (int i = threadIdx.x; i < 512; i += 64) {
        float v = fabsf(b2f(x[i]));
        if (!(v <= 1e6f)) bigf = 1;
    }
    int any = __any(bigf);
    if (threadIdx.x == 0) *flag = any ? 1 : 0;
}

// ---------------------------------------------------------------------------
// Canonicalize to bf16 (no transpose).
// ---------------------------------------------------------------------------
__global__ __launch_bounds__(256) void canon(
    const void* __restrict__ src, u16* __restrict__ dst, int n,
    const int* __restrict__ flag)
{
    int i = (blockIdx.x * 256 + threadIdx.x) * 8;
    if (i >= n) return;
    if (*flag) {
        const float* s = (const float*)src + i;
        f32x4 a = *(const f32x4*)s;
        f32x4 b = *(const f32x4*)(s + 4);
        union { i32x4 v; u16 h[8]; } o;
        o.h[0] = f2b(a[0]); o.h[1] = f2b(a[1]); o.h[2] = f2b(a[2]); o.h[3] = f2b(a[3]);
        o.h[4] = f2b(b[0]); o.h[5] = f2b(b[1]); o.h[6] = f2b(b[2]); o.h[7] = f2b(b[3]);
        *(i32x4*)(dst + i) = o.v;
    } else {
        *(i32x4*)(dst + i) = *(const i32x4*)((const u16*)src + i);
    }
}

// ---------------------------------------------------------------------------
// Fused canonicalize + transpose: src [M][N] -> dst [N][M] bf16.
// ---------------------------------------------------------------------------
__global__ __launch_bounds__(256) void canon_t(
    const void* __restrict__ src, u16* __restrict__ dst, int Mdim, int Ndim,
    const int* __restrict__ flag)
{
    __shared__ __align__(16) u16 t[64 * 72];
    const int m0 = blockIdx.x * 64, n0 = blockIdx.y * 64;
    const int tid = threadIdx.x;
    const bool f = (*flag != 0);
#pragma unroll
    for (int p = 0; p < 2; ++p) {
        int s = tid + p * 256;
        int r = s >> 3, c0 = (s & 7) << 3;
        union { i32x4 v; u16 h[8]; } o;
        if (f) {
            const float* sp = (const float*)src + (size_t)(m0 + r) * Ndim + n0 + c0;
            f32x4 a = *(const f32x4*)sp, b = *(const f32x4*)(sp + 4);
            o.h[0] = f2b(a[0]); o.h[1] = f2b(a[1]); o.h[2] = f2b(a[2]); o.h[3] = f2b(a[3]);
            o.h[4] = f2b(b[0]); o.h[5] = f2b(b[1]); o.h[6] = f2b(b[2]); o.h[7] = f2b(b[3]);
        } else {
            o.v = *(const i32x4*)((const u16*)src + (size_t)(m0 + r) * Ndim + n0 + c0);
        }
        *(i32x4*)(t + r * 72 + c0) = o.v;
    }
    __syncthreads();
#pragma unroll
    for (int p = 0; p < 2; ++p) {
        int s = tid + p * 256;
        int oc = s >> 3, mc = (s & 7) << 3;
        union { i32x4 v; u16 h[8]; } o;
#pragma unroll
        for (int j = 0; j < 8; ++j) o.h[j] = t[(mc + j) * 72 + oc];
        *(i32x4*)(dst + (size_t)(n0 + oc) * Mdim + m0 + mc) = o.v;
    }
}

// ---------------------------------------------------------------------------
// V pre-transpose: qkv[b][s][h*192+128+d] -> vT[h*64+d][b*2048+s].
// ---------------------------------------------------------------------------
__global__ __launch_bounds__(256) void vtrans(
    const u16* __restrict__ qkv, u16* __restrict__ vT)
{
    __shared__ __align__(16) u16 t[64 * 72];
    const int bh = blockIdx.x, b = bh >> 4, h = bh & 15;
    const int s0 = blockIdx.y * 64;
    const int tid = threadIdx.x;
#pragma unroll
    for (int p = 0; p < 2; ++p) {
        int s = tid + p * 256;
        int r = s >> 3, c0 = (s & 7) << 3;
        *(i32x4*)(t + r * 72 + c0) =
            *(const i32x4*)(qkv + (size_t)(b * 2048 + s0 + r) * 3072 + h * 192 + 128 + c0);
    }
    __syncthreads();
#pragma unroll
    for (int p = 0; p < 2; ++p) {
        int s = tid + p * 256;
        int oc = s >> 3, mc = (s & 7) << 3;
        union { i32x4 v; u16 h[8]; } o;
#pragma unroll
        for (int j = 0; j < 8; ++j) o.h[j] = t[(mc + j) * 72 + oc];
        *(i32x4*)(vT + (size_t)(h * 64 + oc) * 8192 + b * 2048 + s0 + mc) = o.v;
    }
}

// ---------------------------------------------------------------------------
// GEMM: C[M,N] = A[M,K] * Bt[N,K]^T, bf16, fp32 acc. 128x128 tile, BK=32.
// m97 pattern: async global_load_lds width-16 staging into unpadded [128][32].
// ---------------------------------------------------------------------------
__global__ __launch_bounds__(256) void gemm_bf16(
    const u16* __restrict__ A, const u16* __restrict__ Bt, u16* __restrict__ C,
    int M, int N, int K)
{
    __shared__ __align__(16) u16 lA[128 * 32];
    __shared__ __align__(16) u16 lB[128 * 32];
    const int tid  = threadIdx.x;
    const int lane = tid & 63;
    const int wave = tid >> 6;
    const int la = lane & 15;
    const int qd = lane >> 4;
    const int m0 = blockIdx.x * 128, n0 = blockIdx.y * 128;
    const int wm = (wave & 1) * 64, wn = (wave >> 1) * 64;

    // async staging: wave w covers rows w*32..w*32+31 (two 16-row calls)
    const int srow = wave * 32 + (lane >> 2);
    const int sseg = (lane & 3) << 3;
    const u16* gA = A  + (size_t)(m0 + srow) * K + sseg;
    const u16* gB = Bt + (size_t)(n0 + srow) * K + sseg;
    u16* lsA = lA + wave * 32 * 32;   // wave-uniform base
    u16* lsB = lB + wave * 32 * 32;

    f32x4 acc[4][4];
    const f32x4 fz = {0.f, 0.f, 0.f, 0.f};
#pragma unroll
    for (int i = 0; i < 4; ++i)
#pragma unroll
        for (int j = 0; j < 4; ++j) acc[i][j] = fz;

    for (int k0 = 0; k0 < K; k0 += 32) {
        __syncthreads();
        async_cp16(gA + k0,            lsA);
        async_cp16(gA + k0 + 16 * K,   lsA + 16 * 32);
        async_cp16(gB + k0,            lsB);
        async_cp16(gB + k0 + 16 * K,   lsB + 16 * 32);
        __syncthreads();

        short8 af[4], bf[4];
#pragma unroll
        for (int i = 0; i < 4; ++i)
            af[i] = *(const short8*)(lA + (wm + i * 16 + la) * 32 + qd * 8);
#pragma unroll
        for (int j = 0; j < 4; ++j)
            bf[j] = *(const short8*)(lB + (wn + j * 16 + la) * 32 + qd * 8);
#pragma unroll
        for (int i = 0; i < 4; ++i)
#pragma unroll
            for (int j = 0; j < 4; ++j)
                acc[i][j] = __builtin_amdgcn_mfma_f32_16x16x32_bf16(
                    af[i], bf[j], acc[i][j], 0, 0, 0);
    }

#pragma unroll
    for (int i = 0; i < 4; ++i)
#pragma unroll
        for (int j = 0; j < 4; ++j)
#pragma unroll
            for (int r = 0; r < 4; ++r) {
                int row = m0 + wm + i * 16 + qd * 4 + r;
                int col = n0 + wn + j * 16 + la;
                C[(size_t)row * N + col] = f2b(acc[i][j][r]);
            }
}

// ---------------------------------------------------------------------------
// MFMA flash attention v3: 128 q-rows/block, 4 waves, wave owns 32 q-rows
// (two fragment sets: q = wave*32+la and wave*32+16+la).
// S^T trick (A=K, B=Q), Q pre-scaled by 0.125 at stage (exact pow2 in bf16).
// K-frag and V-frag each feed 2 MFMAs. 2 barriers/tile. Register prefetch.
// ---------------------------------------------------------------------------
#define S_LEN 2048
#define D3 3072
#define NEG_BIG (-30000.0f)

__global__ __launch_bounds__(256) void attn_fwd(
    const u16* __restrict__ qkv, const u16* __restrict__ vT,
    u16* __restrict__ outp)
{
    __shared__ __align__(16) u16 Qs[128 * 72];  // [q][d], pre-scaled
    __shared__ __align__(16) u16 Ks[64 * 72];   // [kcol][d]
    __shared__ __align__(16) u16 Vts[64 * 72];  // [d][kcol]
    __shared__ __align__(16) u16 Ps[128 * 72];  // [q][kcol] (wave-private rows)
    const int tid  = threadIdx.x;
    const int lane = tid & 63;
    const int wave = tid >> 6;
    const int la = lane & 15;
    const int qd = lane >> 4;
    const int qt = 15 - blockIdx.x;     // big tiles first
    const int bh = blockIdx.y;
    const int b = bh >> 4, h = bh & 15;
    const int q0 = qt * 128;
    const size_t rowb = (size_t)b * S_LEN * D3;
    const int hq = h * 192;
    const u16* vTp = vT + (size_t)(h * 64) * 8192 + b * 2048;

    // stage Q once, scaled by 0.125 (exact in bf16)
#pragma unroll
    for (int p = 0; p < 4; ++p) {
        int slot = tid + p * 256;
        int row = slot >> 3, seg = (slot & 7) << 3;
        union { i32x4 v; u16 s[8]; } u;
        u.v = *(const i32x4*)(qkv + rowb + (size_t)(q0 + row) * D3 + hq + seg);
#pragma unroll
        for (int j = 0; j < 8; ++j) u.s[j] = f2b(b2f(u.s[j]) * 0.125f);
        *(i32x4*)(Qs + row * 72 + seg) = u.v;
    }

    f32x4 O0[4], O1[4];
    const f32x4 fz = {0.f, 0.f, 0.f, 0.f};
#pragma unroll
    for (int jd = 0; jd < 4; ++jd) { O0[jd] = fz; O1[jd] = fz; }
    float m0r = NEG_BIG, l0r = 0.f;   // q = q0 + wave*32 + la
    float m1r = NEG_BIG, l1r = 0.f;   // q = q0 + wave*32 + 16 + la

    const int ktmax = 2 * qt + 1;
    // prefetch tile 0
    i32x4 kreg[2], vreg[2];
#pragma unroll
    for (int p = 0; p < 2; ++p) {
        int slot = tid + p * 256;
        int row = slot >> 3, seg = (slot & 7) << 3;
        kreg[p] = *(const i32x4*)(qkv + rowb + (size_t)row * D3 + hq + 64 + seg);
        vreg[p] = *(const i32x4*)(vTp + (size_t)row * 8192 + seg);
    }

    for (int kt = 0; kt <= ktmax; ++kt) {
        const int k0 = kt * 64;
        __syncthreads();   // prev-iter LDS reads done (covers Q stage at kt=0)
#pragma unroll
        for (int p = 0; p < 2; ++p) {
            int slot = tid + p * 256;
            int row = slot >> 3, seg = (slot & 7) << 3;
            *(i32x4*)(Ks  + row * 72 + seg) = kreg[p];
            *(i32x4*)(Vts + row * 72 + seg) = vreg[p];
        }
        if (kt < ktmax) {
            const int kn = (kt + 1) * 64;
#pragma unroll
            for (int p = 0; p < 2; ++p) {
                int slot = tid + p * 256;
                int row = slot >> 3, seg = (slot & 7) << 3;
                kreg[p] = *(const i32x4*)(qkv + rowb + (size_t)(kn + row) * D3 + hq + 64 + seg);
                vreg[p] = *(const i32x4*)(vTp + (size_t)row * 8192 + kn + seg);
            }
        }
        __syncthreads();   // staging visible

        // ---- S^T = K . Q^T ; s0: q=wave*32+la, s1: q=wave*32+16+la ----
        f32x4 s0[4], s1[4];
#pragma unroll
        for (int jm = 0; jm < 4; ++jm) { s0[jm] = fz; s1[jm] = fz; }
#pragma unroll
        for (int s = 0; s < 2; ++s) {
            short8 bq0 = *(const short8*)(Qs + (wave * 32 + la) * 72 + s * 32 + qd * 8);
            short8 bq1 = *(const short8*)(Qs + (wave * 32 + 16 + la) * 72 + s * 32 + qd * 8);
#pragma unroll
            for (int jm = 0; jm < 4; ++jm) {
                short8 ak = *(const short8*)(Ks + (jm * 16 + la) * 72 + s * 32 + qd * 8);
                s0[jm] = __builtin_amdgcn_mfma_f32_16x16x32_bf16(ak, bq0, s0[jm], 0, 0, 0);
                s1[jm] = __builtin_amdgcn_mfma_f32_16x16x32_bf16(ak, bq1, s1[jm], 0, 0, 0);
            }
        }
        if (kt >= 2 * qt) {   // tiles overlapping the diagonal
            const int qg0 = q0 + wave * 32 + la;
            const int qg1 = qg0 + 16;
#pragma unroll
            for (int jm = 0; jm < 4; ++jm)
#pragma unroll
                for (int r = 0; r < 4; ++r) {
                    int kcg = k0 + jm * 16 + qd * 4 + r;
                    if (kcg > qg0) s0[jm][r] = NEG_BIG;
                    if (kcg > qg1) s1[jm][r] = NEG_BIG;
                }
        }

        // ---- softmax set 0 ----
        float mx0 = fmaxf(fmaxf(fmaxf(s0[0][0], s0[0][1]), fmaxf(s0[0][2], s0[0][3])),
                          fmaxf(fmaxf(s0[1][0], s0[1][1]), fmaxf(s0[1][2], s0[1][3])));
        mx0 = fmaxf(mx0, fmaxf(fmaxf(fmaxf(s0[2][0], s0[2][1]), fmaxf(s0[2][2], s0[2][3])),
                               fmaxf(fmaxf(s0[3][0], s0[3][1]), fmaxf(s0[3][2], s0[3][3]))));
        float mx1 = fmaxf(fmaxf(fmaxf(s1[0][0], s1[0][1]), fmaxf(s1[0][2], s1[0][3])),
                          fmaxf(fmaxf(s1[1][0], s1[1][1]), fmaxf(s1[1][2], s1[1][3])));
        mx1 = fmaxf(mx1, fmaxf(fmaxf(fmaxf(s1[2][0], s1[2][1]), fmaxf(s1[2][2], s1[2][3])),
                               fmaxf(fmaxf(s1[3][0], s1[3][1]), fmaxf(s1[3][2], s1[3][3]))));
        mx0 = fmaxf(mx0, __shfl_xor(mx0, 16)); mx0 = fmaxf(mx0, __shfl_xor(mx0, 32));
        mx1 = fmaxf(mx1, __shfl_xor(mx1, 16)); mx1 = fmaxf(mx1, __shfl_xor(mx1, 32));
        float mn0 = fmaxf(m0r, mx0), mn1 = fmaxf(m1r, mx1);
        float al0 = __expf(m0r - mn0), al1 = __expf(m1r - mn1);
        float sm0 = 0.f, sm1 = 0.f;
#pragma unroll
        for (int jm = 0; jm < 4; ++jm)
#pragma unroll
            for (int r = 0; r < 4; ++r) {
                float p0 = __expf(s0[jm][r] - mn0);
                float p1 = __expf(s1[jm][r] - mn1);
                s0[jm][r] = p0; s1[jm][r] = p1;
                sm0 += p0; sm1 += p1;
            }
        sm0 += __shfl_xor(sm0, 16); sm0 += __shfl_xor(sm0, 32);
        sm1 += __shfl_xor(sm1, 16); sm1 += __shfl_xor(sm1, 32);
        l0r = l0r * al0 + sm0;  m0r = mn0;
        l1r = l1r * al1 + sm1;  m1r = mn1;

        // ---- P -> LDS (packed b64, wave-private rows) ----
#pragma unroll
        for (int jm = 0; jm < 4; ++jm) {
            union { uint2 u; u16 h[4]; } w0, w1;
#pragma unroll
            for (int r = 0; r < 4; ++r) { w0.h[r] = f2b(s0[jm][r]); w1.h[r] = f2b(s1[jm][r]); }
            *(uint2*)(Ps + (wave * 32 + la) * 72 + jm * 16 + qd * 4)      = w0.u;
            *(uint2*)(Ps + (wave * 32 + 16 + la) * 72 + jm * 16 + qd * 4) = w1.u;
        }

        // ---- O rescale (alpha for O-row qd*4+r lives in lane qd*4+r) ----
        float ar0[4], ar1[4];
#pragma unroll
        for (int r = 0; r < 4; ++r) { ar0[r] = __shfl(al0, qd * 4 + r); ar1[r] = __shfl(al1, qd * 4 + r); }
#pragma unroll
        for (int jd = 0; jd < 4; ++jd)
#pragma unroll
            for (int r = 0; r < 4; ++r) { O0[jd][r] *= ar0[r]; O1[jd][r] *= ar1[r]; }

        // ---- PV ----
#pragma unroll
        for (int s = 0; s < 2; ++s) {
            short8 ap0 = *(const short8*)(Ps + (wave * 32 + la) * 72 + s * 32 + qd * 8);
            short8 ap1 = *(const short8*)(Ps + (wave * 32 + 16 + la) * 72 + s * 32 + qd * 8);
#pragma unroll
            for (int jd = 0; jd < 4; ++jd) {
                short8 bv = *(const short8*)(Vts + (jd * 16 + la) * 72 + s * 32 + qd * 8);
                O0[jd] = __builtin_amdgcn_mfma_f32_16x16x32_bf16(ap0, bv, O0[jd], 0, 0, 0);
                O1[jd] = __builtin_amdgcn_mfma_f32_16x16x32_bf16(ap1, bv, O1[jd], 0, 0, 0);
            }
        }
    }

    // epilogue: O0 rows q0+wave*32+qd*4+r, O1 rows +16; col h*64 + jd*16 + la
#pragma unroll
    for (int r = 0; r < 4; ++r) {
        float i0 = 1.f / __shfl(l0r, qd * 4 + r);
        float i1 = 1.f / __shfl(l1r, qd * 4 + r);
        size_t orow0 = (size_t)(b * S_LEN + q0 + wave * 32 + qd * 4 + r) * 1024 + h * 64;
        size_t orow1 = orow0 + (size_t)16 * 1024;
#pragma unroll
        for (int jd = 0; jd < 4; ++jd) {
            outp[orow0 + jd * 16 + la] = f2b(O0[jd][r] * i0);
            outp[orow1 + jd * 16 + la] = f2b(O1[jd][r] * i1);
        }
    }
}

// ---------------------------------------------------------------------------
// y = proj + x0 ; LayerNorm over last dim (1024). Output dtype per wire flag.
// ---------------------------------------------------------------------------
__global__ __launch_bounds__(256) void ln_residual(
    const u16* __restrict__ proj, const u16* __restrict__ x0,
    void* __restrict__ out, const int* __restrict__ flag)
{
    __shared__ float red[8];
    __shared__ float stats[2];
    const size_t base = (size_t)blockIdx.x * 1024 + threadIdx.x * 4;
    union { uint2 u; u16 s[4]; } pa, xa;
    pa.u = *(const uint2*)(proj + base);
    xa.u = *(const uint2*)(x0 + base);
    float y[4];
    float s1 = 0.f, s2 = 0.f;
#pragma unroll
    for (int j = 0; j < 4; ++j) {
        y[j] = b2f(pa.s[j]) + b2f(xa.s[j]);
        s1 += y[j];
        s2 += y[j] * y[j];
    }
#pragma unroll
    for (int off = 32; off > 0; off >>= 1) {
        s1 += __shfl_down(s1, off);
        s2 += __shfl_down(s2, off);
    }
    const int wave = threadIdx.x >> 6, lane = threadIdx.x & 63;
    if (lane == 0) { red[wave * 2] = s1; red[wave * 2 + 1] = s2; }
    __syncthreads();
    if (threadIdx.x == 0) {
        float S1 = red[0] + red[2] + red[4] + red[6];
        float S2 = red[1] + red[3] + red[5] + red[7];
        float mean = S1 * (1.f / 1024.f);
        float var  = fmaxf(S2 * (1.f / 1024.f) - mean * mean, 0.f);
        stats[0] = mean;
        stats[1] = rsqrtf(var + 1e-5f);
    }
    __syncthreads();
    float mean = stats[0], inv = stats[1];
    if (*flag) {
        f32x4 o;
#pragma unroll
        for (int j = 0; j < 4; ++j) o[j] = (y[j] - mean) * inv;
        *(f32x4*)((float*)out + base) = o;
    } else {
        union { uint2 u; u16 s[4]; } o;
#pragma unroll
        for (int j = 0; j < 4; ++j) o.s[j] = f2b((y[j] - mean) * inv);
        *(uint2*)((u16*)out + base) = o.u;
    }
}

// ---------------------------------------------------------------------------
extern "C" void kernel_launch(void* const* d_in, const int* in_sizes, int n_in,
                              void* d_out, int out_size, void* d_ws, size_t ws_size,
                              hipStream_t stream) {
    // d_in[3] = src_mask, all-False per spec -> ignored
    char* ws = (char*)d_ws;
    int* flag = (int*)ws;
    u16* cx0  = (u16*)(ws + 256);                 // 8192x1024  bf16 (16 MB)
    u16* wtin = cx0  + (size_t)8192 * 1024;       // W_in^T [3072][1024] (6 MB)
    u16* wto  = wtin + (size_t)3072 * 1024;       // W_o^T  [1024][1024] (2 MB)
    u16* qkv  = wto  + (size_t)1024 * 1024;       // 8192x3072 (48 MB)
    u16* vT   = qkv  + (size_t)8192 * 3072;       // [16*64][8192] (16 MB)
    u16* attn = vT   + (size_t)1024 * 8192;       // 8192x1024 (16 MB)
    u16* proj = qkv;                              // reuse qkv region (K3 after K2)

    dim3 blk(256);
    probe_dtype<<<1, 64, 0, stream>>>((const u16*)d_in[0], flag);
    canon<<<4096, blk, 0, stream>>>(d_in[0], cx0, 8192 * 1024, flag);
    canon_t<<<dim3(16, 48), blk, 0, stream>>>(d_in[1], wtin, 1024, 3072, flag);
    canon_t<<<dim3(16, 16), blk, 0, stream>>>(d_in[2], wto,  1024, 1024, flag);
    // K1: QKV projection
    gemm_bf16<<<dim3(64, 24), blk, 0, stream>>>(cx0, wtin, qkv, 8192, 3072, 1024);
    // V pre-transpose
    vtrans<<<dim3(64, 32), blk, 0, stream>>>(qkv, vT);
    // K2: causal flash attention (128-row q-tiles)
    attn_fwd<<<dim3(16, 64), blk, 0, stream>>>(qkv, vT, attn);
    // K3: output projection
    gemm_bf16<<<dim3(64, 8), blk, 0, stream>>>(attn, wto, proj, 8192, 1024, 1024);
    // K4: residual + LayerNorm
    ln_residual<<<dim3(8192), blk, 0, stream>>>(proj, cx0, d_out, flag);
}

// Round 7
// 321.710 us; speedup vs baseline: 9.5726x; 1.1569x over previous
//
#include <hip/hip_runtime.h>
#include <hip/hip_bf16.h>

typedef unsigned short u16;
typedef unsigned int u32;
typedef __attribute__((ext_vector_type(8))) short short8;  // bf16x8 MFMA A/B frag
typedef __attribute__((ext_vector_type(4))) float f32x4;   // MFMA acc / float4
typedef __attribute__((ext_vector_type(4))) int i32x4;     // 16B vector ld/st

__device__ __forceinline__ float b2f(u16 u) {
    union { u32 i; float f; } x; x.i = ((u32)u) << 16; return x.f;
}
__device__ __forceinline__ u16 f2b(float f) {
    union { float f; u32 u; } x; x.f = f;
    u32 r = x.u + 0x7fffu + ((x.u >> 16) & 1u);
    return (u16)(r >> 16);
}
// async 16B global->LDS (wave-uniform LDS base + lane*16; m97 pattern)
__device__ __forceinline__ void async_cp16(const u16* g, u16* l) {
    __builtin_amdgcn_global_load_lds(
        (const __attribute__((address_space(1))) void*)g,
        (__attribute__((address_space(3))) void*)l, 16, 0, 0);
}

// ---------------------------------------------------------------------------
// Dtype probe: flag = 1 (fp32 wire) / 0 (bf16 wire).
// ---------------------------------------------------------------------------
__global__ void probe_dtype(const u16* __restrict__ x, int* __restrict__ flag) {
    int bigf = 0;
    for (int i = threadIdx.x; i < 512; i += 64) {
        float v = fabsf(b2f(x[i]));
        if (!(v <= 1e6f)) bigf = 1;
    }
    int any = __any(bigf);
    if (threadIdx.x == 0) *flag = any ? 1 : 0;
}

// ---------------------------------------------------------------------------
// Canonicalize to bf16 (no transpose).
// ---------------------------------------------------------------------------
__global__ __launch_bounds__(256) void canon(
    const void* __restrict__ src, u16* __restrict__ dst, int n,
    const int* __restrict__ flag)
{
    int i = (blockIdx.x * 256 + threadIdx.x) * 8;
    if (i >= n) return;
    if (*flag) {
        const float* s = (const float*)src + i;
        f32x4 a = *(const f32x4*)s;
        f32x4 b = *(const f32x4*)(s + 4);
        union { i32x4 v; u16 h[8]; } o;
        o.h[0] = f2b(a[0]); o.h[1] = f2b(a[1]); o.h[2] = f2b(a[2]); o.h[3] = f2b(a[3]);
        o.h[4] = f2b(b[0]); o.h[5] = f2b(b[1]); o.h[6] = f2b(b[2]); o.h[7] = f2b(b[3]);
        *(i32x4*)(dst + i) = o.v;
    } else {
        *(i32x4*)(dst + i) = *(const i32x4*)((const u16*)src + i);
    }
}

// ---------------------------------------------------------------------------
// Fused canonicalize + transpose: src [M][N] -> dst [N][M] bf16.
// ---------------------------------------------------------------------------
__global__ __launch_bounds__(256) void canon_t(
    const void* __restrict__ src, u16* __restrict__ dst, int Mdim, int Ndim,
    const int* __restrict__ flag)
{
    __shared__ __align__(16) u16 t[64 * 72];
    const int m0 = blockIdx.x * 64, n0 = blockIdx.y * 64;
    const int tid = threadIdx.x;
    const bool f = (*flag != 0);
#pragma unroll
    for (int p = 0; p < 2; ++p) {
        int s = tid + p * 256;
        int r = s >> 3, c0 = (s & 7) << 3;
        union { i32x4 v; u16 h[8]; } o;
        if (f) {
            const float* sp = (const float*)src + (size_t)(m0 + r) * Ndim + n0 + c0;
            f32x4 a = *(const f32x4*)sp, b = *(const f32x4*)(sp + 4);
            o.h[0] = f2b(a[0]); o.h[1] = f2b(a[1]); o.h[2] = f2b(a[2]); o.h[3] = f2b(a[3]);
            o.h[4] = f2b(b[0]); o.h[5] = f2b(b[1]); o.h[6] = f2b(b[2]); o.h[7] = f2b(b[3]);
        } else {
            o.v = *(const i32x4*)((const u16*)src + (size_t)(m0 + r) * Ndim + n0 + c0);
        }
        *(i32x4*)(t + r * 72 + c0) = o.v;
    }
    __syncthreads();
#pragma unroll
    for (int p = 0; p < 2; ++p) {
        int s = tid + p * 256;
        int oc = s >> 3, mc = (s & 7) << 3;
        union { i32x4 v; u16 h[8]; } o;
#pragma unroll
        for (int j = 0; j < 8; ++j) o.h[j] = t[(mc + j) * 72 + oc];
        *(i32x4*)(dst + (size_t)(n0 + oc) * Mdim + m0 + mc) = o.v;
    }
}

// ---------------------------------------------------------------------------
// V pre-transpose: qkv[b][s][h*192+128+d] -> vT[h*64+d][b*2048+s].
// ---------------------------------------------------------------------------
__global__ __launch_bounds__(256) void vtrans(
    const u16* __restrict__ qkv, u16* __restrict__ vT)
{
    __shared__ __align__(16) u16 t[64 * 72];
    const int bh = blockIdx.x, b = bh >> 4, h = bh & 15;
    const int s0 = blockIdx.y * 64;
    const int tid = threadIdx.x;
#pragma unroll
    for (int p = 0; p < 2; ++p) {
        int s = tid + p * 256;
        int r = s >> 3, c0 = (s & 7) << 3;
        *(i32x4*)(t + r * 72 + c0) =
            *(const i32x4*)(qkv + (size_t)(b * 2048 + s0 + r) * 3072 + h * 192 + 128 + c0);
    }
    __syncthreads();
#pragma unroll
    for (int p = 0; p < 2; ++p) {
        int s = tid + p * 256;
        int oc = s >> 3, mc = (s & 7) << 3;
        union { i32x4 v; u16 h[8]; } o;
#pragma unroll
        for (int j = 0; j < 8; ++j) o.h[j] = t[(mc + j) * 72 + oc];
        *(i32x4*)(vT + (size_t)(h * 64 + oc) * 8192 + b * 2048 + s0 + mc) = o.v;
    }
}

// ---------------------------------------------------------------------------
// GEMM: C[M,N] = A[M,K] * Bt[N,K]^T, bf16, fp32 acc. 128x128 tile, BK=32.
// async global_load_lds width-16 staging (m97 pattern). Unchanged from R6.
// ---------------------------------------------------------------------------
__global__ __launch_bounds__(256) void gemm_bf16(
    const u16* __restrict__ A, const u16* __restrict__ Bt, u16* __restrict__ C,
    int M, int N, int K)
{
    __shared__ __align__(16) u16 lA[128 * 32];
    __shared__ __align__(16) u16 lB[128 * 32];
    const int tid  = threadIdx.x;
    const int lane = tid & 63;
    const int wave = tid >> 6;
    const int la = lane & 15;
    const int qd = lane >> 4;
    const int m0 = blockIdx.x * 128, n0 = blockIdx.y * 128;
    const int wm = (wave & 1) * 64, wn = (wave >> 1) * 64;

    const int srow = wave * 32 + (lane >> 2);
    const int sseg = (lane & 3) << 3;
    const u16* gA = A  + (size_t)(m0 + srow) * K + sseg;
    const u16* gB = Bt + (size_t)(n0 + srow) * K + sseg;
    u16* lsA = lA + wave * 32 * 32;
    u16* lsB = lB + wave * 32 * 32;

    f32x4 acc[4][4];
    const f32x4 fz = {0.f, 0.f, 0.f, 0.f};
#pragma unroll
    for (int i = 0; i < 4; ++i)
#pragma unroll
        for (int j = 0; j < 4; ++j) acc[i][j] = fz;

    for (int k0 = 0; k0 < K; k0 += 32) {
        __syncthreads();
        async_cp16(gA + k0,            lsA);
        async_cp16(gA + k0 + 16 * K,   lsA + 16 * 32);
        async_cp16(gB + k0,            lsB);
        async_cp16(gB + k0 + 16 * K,   lsB + 16 * 32);
        __syncthreads();

        short8 af[4], bf[4];
#pragma unroll
        for (int i = 0; i < 4; ++i)
            af[i] = *(const short8*)(lA + (wm + i * 16 + la) * 32 + qd * 8);
#pragma unroll
        for (int j = 0; j < 4; ++j)
            bf[j] = *(const short8*)(lB + (wn + j * 16 + la) * 32 + qd * 8);
#pragma unroll
        for (int i = 0; i < 4; ++i)
#pragma unroll
            for (int j = 0; j < 4; ++j)
                acc[i][j] = __builtin_amdgcn_mfma_f32_16x16x32_bf16(
                    af[i], bf[j], acc[i][j], 0, 0, 0);
    }

#pragma unroll
    for (int i = 0; i < 4; ++i)
#pragma unroll
        for (int j = 0; j < 4; ++j)
#pragma unroll
            for (int r = 0; r < 4; ++r) {
                int row = m0 + wm + i * 16 + qd * 4 + r;
                int col = n0 + wn + j * 16 + la;
                C[(size_t)row * N + col] = f2b(acc[i][j][r]);
            }
}

// ---------------------------------------------------------------------------
// MFMA flash attention v4: 64-row q-tiles, TILE PAIRING for perfect balance.
// Block x processes q-tiles {x, 31-x} sequentially -> every block does
// exactly 33 k-iterations. Q held in REGISTERS (B-frag direct from global,
// scale 0.125 folded in) -> no Qs LDS. LDS = Ks+Vts+Ps = 27.6 KB ->
// 5 blocks/CU. S^T trick (A=K, B=Q); wave owns q-rows wave*16+la.
// ---------------------------------------------------------------------------
#define S_LEN 2048
#define D3 3072
#define NEG_BIG (-30000.0f)

__global__ __launch_bounds__(256, 5) void attn_fwd(
    const u16* __restrict__ qkv, const u16* __restrict__ vT,
    u16* __restrict__ outp)
{
    __shared__ __align__(16) u16 Ks[64 * 72];   // [kcol][d]
    __shared__ __align__(16) u16 Vts[64 * 72];  // [d][kcol]
    __shared__ __align__(16) u16 Ps[64 * 72];   // [q][kcol] (wave-private rows)
    const int tid  = threadIdx.x;
    const int lane = tid & 63;
    const int wave = tid >> 6;
    const int la = lane & 15;
    const int qd = lane >> 4;
    const int bh = blockIdx.y;
    const int b = bh >> 4, h = bh & 15;
    const size_t rowb = (size_t)b * S_LEN * D3;
    const int hq = h * 192;
    const u16* vTp = vT + (size_t)(h * 64) * 8192 + b * 2048;
    const f32x4 fz = {0.f, 0.f, 0.f, 0.f};

    // staging slots (same for K and V): 2 x i32x4 per thread
    const int srow0 = tid >> 3,        sseg0 = (tid & 7) << 3;
    const int srow1 = (tid + 256) >> 3, sseg1 = (tid & 7) << 3;

#pragma unroll
    for (int seg = 0; seg < 2; ++seg) {
        const int qt = seg == 0 ? (int)blockIdx.x : 31 - (int)blockIdx.x;
        const int q0 = qt * 64;
        const int qg = q0 + wave * 16 + la;   // this lane's q-row

        // Q fragments in registers, scaled by 0.125 (exact pow2 in bf16)
        short8 bq[2];
#pragma unroll
        for (int s = 0; s < 2; ++s) {
            union { short8 v; u16 h[8]; } u;
            u.v = *(const short8*)(qkv + rowb + (size_t)qg * D3 + hq + s * 32 + qd * 8);
#pragma unroll
            for (int j = 0; j < 8; ++j) u.h[j] = f2b(b2f(u.h[j]) * 0.125f);
            bq[s] = u.v;
        }

        f32x4 Oacc[4];
#pragma unroll
        for (int jd = 0; jd < 4; ++jd) Oacc[jd] = fz;
        float m_run = NEG_BIG, l_run = 0.f;

        // prefetch kt=0
        i32x4 kreg[2], vreg[2];
        kreg[0] = *(const i32x4*)(qkv + rowb + (size_t)srow0 * D3 + hq + 64 + sseg0);
        kreg[1] = *(const i32x4*)(qkv + rowb + (size_t)srow1 * D3 + hq + 64 + sseg1);
        vreg[0] = *(const i32x4*)(vTp + (size_t)srow0 * 8192 + sseg0);
        vreg[1] = *(const i32x4*)(vTp + (size_t)srow1 * 8192 + sseg1);

        for (int kt = 0; kt <= qt; ++kt) {
            const int k0 = kt * 64;
            __syncthreads();   // prev-iter (or prev-seg) LDS reads done
            *(i32x4*)(Ks  + srow0 * 72 + sseg0) = kreg[0];
            *(i32x4*)(Ks  + srow1 * 72 + sseg1) = kreg[1];
            *(i32x4*)(Vts + srow0 * 72 + sseg0) = vreg[0];
            *(i32x4*)(Vts + srow1 * 72 + sseg1) = vreg[1];
            if (kt < qt) {
                const int kn = k0 + 64;
                kreg[0] = *(const i32x4*)(qkv + rowb + (size_t)(kn + srow0) * D3 + hq + 64 + sseg0);
                kreg[1] = *(const i32x4*)(qkv + rowb + (size_t)(kn + srow1) * D3 + hq + 64 + sseg1);
                vreg[0] = *(const i32x4*)(vTp + (size_t)srow0 * 8192 + kn + sseg0);
                vreg[1] = *(const i32x4*)(vTp + (size_t)srow1 * 8192 + kn + sseg1);
            }
            __syncthreads();   // staging visible

            // ---- S^T = K . Q^T : sacc[jm][r] = S[q=la-row][kc=jm*16+qd*4+r]
            f32x4 sacc[4];
#pragma unroll
            for (int jm = 0; jm < 4; ++jm) sacc[jm] = fz;
#pragma unroll
            for (int s = 0; s < 2; ++s) {
#pragma unroll
                for (int jm = 0; jm < 4; ++jm) {
                    short8 ak = *(const short8*)(Ks + (jm * 16 + la) * 72 + s * 32 + qd * 8);
                    sacc[jm] = __builtin_amdgcn_mfma_f32_16x16x32_bf16(ak, bq[s], sacc[jm], 0, 0, 0);
                }
            }
            if (kt == qt) {   // diagonal tile: causal mask
#pragma unroll
                for (int jm = 0; jm < 4; ++jm)
#pragma unroll
                    for (int r = 0; r < 4; ++r)
                        if (k0 + jm * 16 + qd * 4 + r > qg) sacc[jm][r] = NEG_BIG;
            }

            // ---- softmax: in-reg reduce + 2 shuffles over qd ----
            float mx = fmaxf(fmaxf(fmaxf(sacc[0][0], sacc[0][1]), fmaxf(sacc[0][2], sacc[0][3])),
                             fmaxf(fmaxf(sacc[1][0], sacc[1][1]), fmaxf(sacc[1][2], sacc[1][3])));
            mx = fmaxf(mx, fmaxf(fmaxf(fmaxf(sacc[2][0], sacc[2][1]), fmaxf(sacc[2][2], sacc[2][3])),
                                 fmaxf(fmaxf(sacc[3][0], sacc[3][1]), fmaxf(sacc[3][2], sacc[3][3]))));
            mx = fmaxf(mx, __shfl_xor(mx, 16));
            mx = fmaxf(mx, __shfl_xor(mx, 32));
            float mnew = fmaxf(m_run, mx);
            float al   = __expf(m_run - mnew);
            float ssum = 0.f;
#pragma unroll
            for (int jm = 0; jm < 4; ++jm)
#pragma unroll
                for (int r = 0; r < 4; ++r) {
                    float pv = __expf(sacc[jm][r] - mnew);
                    sacc[jm][r] = pv;
                    ssum += pv;
                }
            ssum += __shfl_xor(ssum, 16);
            ssum += __shfl_xor(ssum, 32);
            l_run = l_run * al + ssum;
            m_run = mnew;

            // ---- P -> LDS (packed b64, wave-private rows) ----
#pragma unroll
            for (int jm = 0; jm < 4; ++jm) {
                union { uint2 u; u16 h[4]; } w;
#pragma unroll
                for (int r = 0; r < 4; ++r) w.h[r] = f2b(sacc[jm][r]);
                *(uint2*)(Ps + (wave * 16 + la) * 72 + jm * 16 + qd * 4) = w.u;
            }

            // ---- O rescale ----
            float ar[4];
#pragma unroll
            for (int r = 0; r < 4; ++r) ar[r] = __shfl(al, qd * 4 + r);
#pragma unroll
            for (int jd = 0; jd < 4; ++jd)
#pragma unroll
                for (int r = 0; r < 4; ++r) Oacc[jd][r] *= ar[r];

            // ---- PV ----
#pragma unroll
            for (int s = 0; s < 2; ++s) {
                short8 ap = *(const short8*)(Ps + (wave * 16 + la) * 72 + s * 32 + qd * 8);
#pragma unroll
                for (int jd = 0; jd < 4; ++jd) {
                    short8 bv = *(const short8*)(Vts + (jd * 16 + la) * 72 + s * 32 + qd * 8);
                    Oacc[jd] = __builtin_amdgcn_mfma_f32_16x16x32_bf16(ap, bv, Oacc[jd], 0, 0, 0);
                }
            }
        }

        // epilogue: O row q = q0 + wave*16 + qd*4 + r, col h*64 + jd*16 + la
#pragma unroll
        for (int r = 0; r < 4; ++r) {
            float lr = __shfl(l_run, qd * 4 + r);
            float inv = 1.f / lr;
            size_t orow = (size_t)(b * S_LEN + q0 + wave * 16 + qd * 4 + r) * 1024 + h * 64;
#pragma unroll
            for (int jd = 0; jd < 4; ++jd)
                outp[orow + jd * 16 + la] = f2b(Oacc[jd][r] * inv);
        }
    }
}

// ---------------------------------------------------------------------------
// y = proj + x0 ; LayerNorm over last dim (1024). Output dtype per wire flag.
// ---------------------------------------------------------------------------
__global__ __launch_bounds__(256) void ln_residual(
    const u16* __restrict__ proj, const u16* __restrict__ x0,
    void* __restrict__ out, const int* __restrict__ flag)
{
    __shared__ float red[8];
    __shared__ float stats[2];
    const size_t base = (size_t)blockIdx.x * 1024 + threadIdx.x * 4;
    union { uint2 u; u16 s[4]; } pa, xa;
    pa.u = *(const uint2*)(proj + base);
    xa.u = *(const uint2*)(x0 + base);
    float y[4];
    float s1 = 0.f, s2 = 0.f;
#pragma unroll
    for (int j = 0; j < 4; ++j) {
        y[j] = b2f(pa.s[j]) + b2f(xa.s[j]);
        s1 += y[j];
        s2 += y[j] * y[j];
    }
#pragma unroll
    for (int off = 32; off > 0; off >>= 1) {
        s1 += __shfl_down(s1, off);
        s2 += __shfl_down(s2, off);
    }
    const int wave = threadIdx.x >> 6, lane = threadIdx.x & 63;
    if (lane == 0) { red[wave * 2] = s1; red[wave * 2 + 1] = s2; }
    __syncthreads();
    if (threadIdx.x == 0) {
        float S1 = red[0] + red[2] + red[4] + red[6];
        float S2 = red[1] + red[3] + red[5] + red[7];
        float mean = S1 * (1.f / 1024.f);
        float var  = fmaxf(S2 * (1.f / 1024.f) - mean * mean, 0.f);
        stats[0] = mean;
        stats[1] = rsqrtf(var + 1e-5f);
    }
    __syncthreads();
    float mean = stats[0], inv = stats[1];
    if (*flag) {
        f32x4 o;
#pragma unroll
        for (int j = 0; j < 4; ++j) o[j] = (y[j] - mean) * inv;
        *(f32x4*)((float*)out + base) = o;
    } else {
        union { uint2 u; u16 s[4]; } o;
#pragma unroll
        for (int j = 0; j < 4; ++j) o.s[j] = f2b((y[j] - mean) * inv);
        *(uint2*)((u16*)out + base) = o.u;
    }
}

// ---------------------------------------------------------------------------
extern "C" void kernel_launch(void* const* d_in, const int* in_sizes, int n_in,
                              void* d_out, int out_size, void* d_ws, size_t ws_size,
                              hipStream_t stream) {
    // d_in[3] = src_mask, all-False per spec -> ignored
    char* ws = (char*)d_ws;
    int* flag = (int*)ws;
    u16* cx0  = (u16*)(ws + 256);                 // 8192x1024  bf16 (16 MB)
    u16* wtin = cx0  + (size_t)8192 * 1024;       // W_in^T [3072][1024] (6 MB)
    u16* wto  = wtin + (size_t)3072 * 1024;       // W_o^T  [1024][1024] (2 MB)
    u16* qkv  = wto  + (size_t)1024 * 1024;       // 8192x3072 (48 MB)
    u16* vT   = qkv  + (size_t)8192 * 3072;       // [16*64][8192] (16 MB)
    u16* attn = vT   + (size_t)1024 * 8192;       // 8192x1024 (16 MB)
    u16* proj = qkv;                              // reuse qkv region (K3 after K2)

    dim3 blk(256);
    probe_dtype<<<1, 64, 0, stream>>>((const u16*)d_in[0], flag);
    canon<<<4096, blk, 0, stream>>>(d_in[0], cx0, 8192 * 1024, flag);
    canon_t<<<dim3(16, 48), blk, 0, stream>>>(d_in[1], wtin, 1024, 3072, flag);
    canon_t<<<dim3(16, 16), blk, 0, stream>>>(d_in[2], wto,  1024, 1024, flag);
    // K1: QKV projection
    gemm_bf16<<<dim3(64, 24), blk, 0, stream>>>(cx0, wtin, qkv, 8192, 3072, 1024);
    // V pre-transpose
    vtrans<<<dim3(64, 32), blk, 0, stream>>>(qkv, vT);
    // K2: causal flash attention (paired 64-row q-tiles, balanced)
    attn_fwd<<<dim3(16, 64), blk, 0, stream>>>(qkv, vT, attn);
    // K3: output projection
    gemm_bf16<<<dim3(64, 8), blk, 0, stream>>>(attn, wto, proj, 8192, 1024, 1024);
    // K4: residual + LayerNorm
    ln_residual<<<dim3(8192), blk, 0, stream>>>(proj, cx0, d_out, flag);
}

// Round 8
// 297.460 us; speedup vs baseline: 10.3530x; 1.0815x over previous
//
#include <hip/hip_runtime.h>
#include <hip/hip_bf16.h>

typedef unsigned short u16;
typedef unsigned int u32;
typedef __attribute__((ext_vector_type(8))) short short8;  // bf16x8 MFMA A/B frag
typedef __attribute__((ext_vector_type(4))) float f32x4;   // MFMA acc / float4
typedef __attribute__((ext_vector_type(4))) int i32x4;     // 16B vector ld/st

__device__ __forceinline__ float b2f(u16 u) {
    union { u32 i; float f; } x; x.i = ((u32)u) << 16; return x.f;
}
__device__ __forceinline__ u16 f2b(float f) {
    union { float f; u32 u; } x; x.f = f;
    u32 r = x.u + 0x7fffu + ((x.u >> 16) & 1u);
    return (u16)(r >> 16);
}
// packed f32x2 -> bf16x2 (v_cvt_pk_bf16_f32), lo = a
__device__ __forceinline__ u32 pkbf(float a, float b) {
    union { __hip_bfloat162 h; u32 u; } x;
    x.h = __float22bfloat162_rn(make_float2(a, b));
    return x.u;
}
// async 16B global->LDS (wave-uniform LDS base + lane*16; m97 pattern)
__device__ __forceinline__ void async_cp16(const u16* g, u16* l) {
    __builtin_amdgcn_global_load_lds(
        (const __attribute__((address_space(1))) void*)g,
        (__attribute__((address_space(3))) void*)l, 16, 0, 0);
}

// ---------------------------------------------------------------------------
// Dtype probe: flag = 1 (fp32 wire) / 0 (bf16 wire).
// ---------------------------------------------------------------------------
__global__ void probe_dtype(const u16* __restrict__ x, int* __restrict__ flag) {
    int bigf = 0;
    for (int i = threadIdx.x; i < 512; i += 64) {
        float v = fabsf(b2f(x[i]));
        if (!(v <= 1e6f)) bigf = 1;
    }
    int any = __any(bigf);
    if (threadIdx.x == 0) *flag = any ? 1 : 0;
}

// ---------------------------------------------------------------------------
// Canonicalize to bf16 (no transpose).
// ---------------------------------------------------------------------------
__global__ __launch_bounds__(256) void canon(
    const void* __restrict__ src, u16* __restrict__ dst, int n,
    const int* __restrict__ flag)
{
    int i = (blockIdx.x * 256 + threadIdx.x) * 8;
    if (i >= n) return;
    if (*flag) {
        const float* s = (const float*)src + i;
        f32x4 a = *(const f32x4*)s;
        f32x4 b = *(const f32x4*)(s + 4);
        union { i32x4 v; u32 w[4]; } o;
        o.w[0] = pkbf(a[0], a[1]); o.w[1] = pkbf(a[2], a[3]);
        o.w[2] = pkbf(b[0], b[1]); o.w[3] = pkbf(b[2], b[3]);
        *(i32x4*)(dst + i) = o.v;
    } else {
        *(i32x4*)(dst + i) = *(const i32x4*)((const u16*)src + i);
    }
}

// ---------------------------------------------------------------------------
// Fused canonicalize + transpose: src [M][N] -> dst [N][M] bf16.
// ---------------------------------------------------------------------------
__global__ __launch_bounds__(256) void canon_t(
    const void* __restrict__ src, u16* __restrict__ dst, int Mdim, int Ndim,
    const int* __restrict__ flag)
{
    __shared__ __align__(16) u16 t[64 * 72];
    const int m0 = blockIdx.x * 64, n0 = blockIdx.y * 64;
    const int tid = threadIdx.x;
    const bool f = (*flag != 0);
#pragma unroll
    for (int p = 0; p < 2; ++p) {
        int s = tid + p * 256;
        int r = s >> 3, c0 = (s & 7) << 3;
        union { i32x4 v; u32 w[4]; } o;
        if (f) {
            const float* sp = (const float*)src + (size_t)(m0 + r) * Ndim + n0 + c0;
            f32x4 a = *(const f32x4*)sp, b = *(const f32x4*)(sp + 4);
            o.w[0] = pkbf(a[0], a[1]); o.w[1] = pkbf(a[2], a[3]);
            o.w[2] = pkbf(b[0], b[1]); o.w[3] = pkbf(b[2], b[3]);
        } else {
            o.v = *(const i32x4*)((const u16*)src + (size_t)(m0 + r) * Ndim + n0 + c0);
        }
        *(i32x4*)(t + r * 72 + c0) = o.v;
    }
    __syncthreads();
#pragma unroll
    for (int p = 0; p < 2; ++p) {
        int s = tid + p * 256;
        int oc = s >> 3, mc = (s & 7) << 3;
        union { i32x4 v; u16 h[8]; } o;
#pragma unroll
        for (int j = 0; j < 8; ++j) o.h[j] = t[(mc + j) * 72 + oc];
        *(i32x4*)(dst + (size_t)(n0 + oc) * Mdim + m0 + mc) = o.v;
    }
}

// ---------------------------------------------------------------------------
// V pre-transpose: qkv[b][s][h*192+128+d] -> vT[h*64+d][b*2048+s].
// ---------------------------------------------------------------------------
__global__ __launch_bounds__(256) void vtrans(
    const u16* __restrict__ qkv, u16* __restrict__ vT)
{
    __shared__ __align__(16) u16 t[64 * 72];
    const int bh = blockIdx.x, b = bh >> 4, h = bh & 15;
    const int s0 = blockIdx.y * 64;
    const int tid = threadIdx.x;
#pragma unroll
    for (int p = 0; p < 2; ++p) {
        int s = tid + p * 256;
        int r = s >> 3, c0 = (s & 7) << 3;
        *(i32x4*)(t + r * 72 + c0) =
            *(const i32x4*)(qkv + (size_t)(b * 2048 + s0 + r) * 3072 + h * 192 + 128 + c0);
    }
    __syncthreads();
#pragma unroll
    for (int p = 0; p < 2; ++p) {
        int s = tid + p * 256;
        int oc = s >> 3, mc = (s & 7) << 3;
        union { i32x4 v; u16 h[8]; } o;
#pragma unroll
        for (int j = 0; j < 8; ++j) o.h[j] = t[(mc + j) * 72 + oc];
        *(i32x4*)(vT + (size_t)(h * 64 + oc) * 8192 + b * 2048 + s0 + mc) = o.v;
    }
}

// ---------------------------------------------------------------------------
// GEMM v2: C[M,N] = A[M,K] * Bt[N,K]^T, bf16, fp32 acc. 128x128 tile, BK=64.
// XOR-swizzled async staging: LDS[row][chunk_phys] holds logical chunk
// chunk_phys ^ (row&7) (swizzle folded into the global source address, so
// global_load_lds's lane*16 dst rule is preserved). Frag reads at chunk
// (s*4+qd)^(la&7) span all 32 banks -> conflict-free. 16 K-iterations.
// ---------------------------------------------------------------------------
__global__ __launch_bounds__(256) void gemm_bf16(
    const u16* __restrict__ A, const u16* __restrict__ Bt, u16* __restrict__ C,
    int M, int N, int K)
{
    __shared__ __align__(16) u16 lA[128 * 64];   // 16 KB
    __shared__ __align__(16) u16 lB[128 * 64];   // 16 KB
    const int tid  = threadIdx.x;
    const int lane = tid & 63;
    const int wave = tid >> 6;
    const int la = lane & 15;
    const int qd = lane >> 4;
    const int m0 = blockIdx.x * 128, n0 = blockIdx.y * 128;
    const int wm = (wave & 1) * 64, wn = (wave >> 1) * 64;

    // staging: call c covers rows wave*32 + c*8 + (lane>>3); lane's 16B chunk
    // at phys (lane&7) sources logical chunk (lane&7)^(lane>>3).
    const int srow = lane >> 3;
    const int scol = ((lane & 7) ^ (lane >> 3)) << 3;   // u16 units
    const u16* gA = A  + (size_t)(m0 + wave * 32 + srow) * K + scol;
    const u16* gB = Bt + (size_t)(n0 + wave * 32 + srow) * K + scol;
    u16* lsA = lA + wave * 32 * 64;
    u16* lsB = lB + wave * 32 * 64;

    f32x4 acc[4][4];
    const f32x4 fz = {0.f, 0.f, 0.f, 0.f};
#pragma unroll
    for (int i = 0; i < 4; ++i)
#pragma unroll
        for (int j = 0; j < 4; ++j) acc[i][j] = fz;

    for (int k0 = 0; k0 < K; k0 += 64) {
        __syncthreads();
#pragma unroll
        for (int c = 0; c < 4; ++c) {
            async_cp16(gA + k0 + (size_t)(c * 8) * K, lsA + c * 8 * 64);
            async_cp16(gB + k0 + (size_t)(c * 8) * K, lsB + c * 8 * 64);
        }
        __syncthreads();

#pragma unroll
        for (int s = 0; s < 2; ++s) {
            short8 af[4], bf[4];
#pragma unroll
            for (int i = 0; i < 4; ++i) {
                int row = wm + i * 16 + la;
                af[i] = *(const short8*)(lA + row * 64 + (((s * 4 + qd) ^ (la & 7)) << 3));
            }
#pragma unroll
            for (int j = 0; j < 4; ++j) {
                int row = wn + j * 16 + la;
                bf[j] = *(const short8*)(lB + row * 64 + (((s * 4 + qd) ^ (la & 7)) << 3));
            }
#pragma unroll
            for (int i = 0; i < 4; ++i)
#pragma unroll
                for (int j = 0; j < 4; ++j)
                    acc[i][j] = __builtin_amdgcn_mfma_f32_16x16x32_bf16(
                        af[i], bf[j], acc[i][j], 0, 0, 0);
        }
    }

#pragma unroll
    for (int i = 0; i < 4; ++i)
#pragma unroll
        for (int j = 0; j < 4; ++j)
#pragma unroll
            for (int r = 0; r < 4; ++r) {
                int row = m0 + wm + i * 16 + qd * 4 + r;
                int col = n0 + wn + j * 16 + la;
                C[(size_t)row * N + col] = f2b(acc[i][j][r]);
            }
}

// ---------------------------------------------------------------------------
// MFMA flash attention v5: paired 64-row q-tiles (perfect balance) +
// XCD-aware (pair,bh) remap: all 16 pair-blocks of one bh land on one XCD
// (lin%8 heuristic) -> K/V working set ~4 MB/XCD stays in L2.
// Q in registers; S^T trick; packed bf16 P-conversion.
// ---------------------------------------------------------------------------
#define S_LEN 2048
#define D3 3072
#define NEG_BIG (-30000.0f)

__global__ __launch_bounds__(256, 5) void attn_fwd(
    const u16* __restrict__ qkv, const u16* __restrict__ vT,
    u16* __restrict__ outp)
{
    __shared__ __align__(16) u16 Ks[64 * 72];   // [kcol][d]
    __shared__ __align__(16) u16 Vts[64 * 72];  // [d][kcol]
    __shared__ __align__(16) u16 Ps[64 * 72];   // [q][kcol] (wave-private rows)
    const int tid  = threadIdx.x;
    const int lane = tid & 63;
    const int wave = tid >> 6;
    const int la = lane & 15;
    const int qd = lane >> 4;
    // XCD swizzle: lin -> (xcd, idx); bh grouped per XCD
    const int lin = blockIdx.y * 16 + blockIdx.x;
    const int xcd = lin & 7, idx = lin >> 3;
    const int bh = xcd * 8 + (idx >> 4);
    const int px = idx & 15;                 // pair index
    const int b = bh >> 4, h = bh & 15;
    const size_t rowb = (size_t)b * S_LEN * D3;
    const int hq = h * 192;
    const u16* vTp = vT + (size_t)(h * 64) * 8192 + b * 2048;
    const f32x4 fz = {0.f, 0.f, 0.f, 0.f};

    const int srow0 = tid >> 3,         sseg0 = (tid & 7) << 3;
    const int srow1 = (tid + 256) >> 3, sseg1 = (tid & 7) << 3;

#pragma unroll
    for (int seg = 0; seg < 2; ++seg) {
        const int qt = seg == 0 ? px : 31 - px;
        const int q0 = qt * 64;
        const int qg = q0 + wave * 16 + la;   // this lane's q-row

        // Q fragments in registers, scaled by 0.125 (exact pow2 in bf16)
        short8 bq[2];
#pragma unroll
        for (int s = 0; s < 2; ++s) {
            union { short8 v; u16 h[8]; } u;
            u.v = *(const short8*)(qkv + rowb + (size_t)qg * D3 + hq + s * 32 + qd * 8);
#pragma unroll
            for (int j = 0; j < 8; ++j) u.h[j] = f2b(b2f(u.h[j]) * 0.125f);
            bq[s] = u.v;
        }

        f32x4 Oacc[4];
#pragma unroll
        for (int jd = 0; jd < 4; ++jd) Oacc[jd] = fz;
        float m_run = NEG_BIG, l_run = 0.f;

        // prefetch kt=0
        i32x4 kreg[2], vreg[2];
        kreg[0] = *(const i32x4*)(qkv + rowb + (size_t)srow0 * D3 + hq + 64 + sseg0);
        kreg[1] = *(const i32x4*)(qkv + rowb + (size_t)srow1 * D3 + hq + 64 + sseg1);
        vreg[0] = *(const i32x4*)(vTp + (size_t)srow0 * 8192 + sseg0);
        vreg[1] = *(const i32x4*)(vTp + (size_t)srow1 * 8192 + sseg1);

        for (int kt = 0; kt <= qt; ++kt) {
            const int k0 = kt * 64;
            __syncthreads();   // prev-iter (or prev-seg) LDS reads done
            *(i32x4*)(Ks  + srow0 * 72 + sseg0) = kreg[0];
            *(i32x4*)(Ks  + srow1 * 72 + sseg1) = kreg[1];
            *(i32x4*)(Vts + srow0 * 72 + sseg0) = vreg[0];
            *(i32x4*)(Vts + srow1 * 72 + sseg1) = vreg[1];
            if (kt < qt) {
                const int kn = k0 + 64;
                kreg[0] = *(const i32x4*)(qkv + rowb + (size_t)(kn + srow0) * D3 + hq + 64 + sseg0);
                kreg[1] = *(const i32x4*)(qkv + rowb + (size_t)(kn + srow1) * D3 + hq + 64 + sseg1);
                vreg[0] = *(const i32x4*)(vTp + (size_t)srow0 * 8192 + kn + sseg0);
                vreg[1] = *(const i32x4*)(vTp + (size_t)srow1 * 8192 + kn + sseg1);
            }
            __syncthreads();   // staging visible

            // ---- S^T = K . Q^T ----
            f32x4 sacc[4];
#pragma unroll
            for (int jm = 0; jm < 4; ++jm) sacc[jm] = fz;
#pragma unroll
            for (int s = 0; s < 2; ++s) {
#pragma unroll
                for (int jm = 0; jm < 4; ++jm) {
                    short8 ak = *(const short8*)(Ks + (jm * 16 + la) * 72 + s * 32 + qd * 8);
                    sacc[jm] = __builtin_amdgcn_mfma_f32_16x16x32_bf16(ak, bq[s], sacc[jm], 0, 0, 0);
                }
            }
            if (kt == qt) {   // diagonal tile: causal mask
#pragma unroll
                for (int jm = 0; jm < 4; ++jm)
#pragma unroll
                    for (int r = 0; r < 4; ++r)
                        if (k0 + jm * 16 + qd * 4 + r > qg) sacc[jm][r] = NEG_BIG;
            }

            // ---- softmax: in-reg reduce + 2 shuffles over qd ----
            float mx = fmaxf(fmaxf(fmaxf(sacc[0][0], sacc[0][1]), fmaxf(sacc[0][2], sacc[0][3])),
                             fmaxf(fmaxf(sacc[1][0], sacc[1][1]), fmaxf(sacc[1][2], sacc[1][3])));
            mx = fmaxf(mx, fmaxf(fmaxf(fmaxf(sacc[2][0], sacc[2][1]), fmaxf(sacc[2][2], sacc[2][3])),
                                 fmaxf(fmaxf(sacc[3][0], sacc[3][1]), fmaxf(sacc[3][2], sacc[3][3]))));
            mx = fmaxf(mx, __shfl_xor(mx, 16));
            mx = fmaxf(mx, __shfl_xor(mx, 32));
            float mnew = fmaxf(m_run, mx);
            float al   = __expf(m_run - mnew);
            float ssum = 0.f;
#pragma unroll
            for (int jm = 0; jm < 4; ++jm)
#pragma unroll
                for (int r = 0; r < 4; ++r) {
                    float pv = __expf(sacc[jm][r] - mnew);
                    sacc[jm][r] = pv;
                    ssum += pv;
                }
            ssum += __shfl_xor(ssum, 16);
            ssum += __shfl_xor(ssum, 32);
            l_run = l_run * al + ssum;
            m_run = mnew;

            // ---- P -> LDS (packed cvt + b64 writes, wave-private rows) ----
#pragma unroll
            for (int jm = 0; jm < 4; ++jm) {
                uint2 w;
                w.x = pkbf(sacc[jm][0], sacc[jm][1]);
                w.y = pkbf(sacc[jm][2], sacc[jm][3]);
                *(uint2*)(Ps + (wave * 16 + la) * 72 + jm * 16 + qd * 4) = w;
            }

            // ---- O rescale ----
            float ar[4];
#pragma unroll
            for (int r = 0; r < 4; ++r) ar[r] = __shfl(al, qd * 4 + r);
#pragma unroll
            for (int jd = 0; jd < 4; ++jd)
#pragma unroll
                for (int r = 0; r < 4; ++r) Oacc[jd][r] *= ar[r];

            // ---- PV ----
#pragma unroll
            for (int s = 0; s < 2; ++s) {
                short8 ap = *(const short8*)(Ps + (wave * 16 + la) * 72 + s * 32 + qd * 8);
#pragma unroll
                for (int jd = 0; jd < 4; ++jd) {
                    short8 bv = *(const short8*)(Vts + (jd * 16 + la) * 72 + s * 32 + qd * 8);
                    Oacc[jd] = __builtin_amdgcn_mfma_f32_16x16x32_bf16(ap, bv, Oacc[jd], 0, 0, 0);
                }
            }
        }

        // epilogue
#pragma unroll
        for (int r = 0; r < 4; ++r) {
            float lr = __shfl(l_run, qd * 4 + r);
            float inv = 1.f / lr;
            size_t orow = (size_t)(b * S_LEN + q0 + wave * 16 + qd * 4 + r) * 1024 + h * 64;
#pragma unroll
            for (int jd = 0; jd < 4; ++jd)
                outp[orow + jd * 16 + la] = f2b(Oacc[jd][r] * inv);
        }
    }
}

// ---------------------------------------------------------------------------
// y = proj + x0 ; LayerNorm over last dim (1024). Output dtype per wire flag.
// ---------------------------------------------------------------------------
__global__ __launch_bounds__(256) void ln_residual(
    const u16* __restrict__ proj, const u16* __restrict__ x0,
    void* __restrict__ out, const int* __restrict__ flag)
{
    __shared__ float red[8];
    __shared__ float stats[2];
    const size_t base = (size_t)blockIdx.x * 1024 + threadIdx.x * 4;
    union { uint2 u; u16 s[4]; } pa, xa;
    pa.u = *(const uint2*)(proj + base);
    xa.u = *(const uint2*)(x0 + base);
    float y[4];
    float s1 = 0.f, s2 = 0.f;
#pragma unroll
    for (int j = 0; j < 4; ++j) {
        y[j] = b2f(pa.s[j]) + b2f(xa.s[j]);
        s1 += y[j];
        s2 += y[j] * y[j];
    }
#pragma unroll
    for (int off = 32; off > 0; off >>= 1) {
        s1 += __shfl_down(s1, off);
        s2 += __shfl_down(s2, off);
    }
    const int wave = threadIdx.x >> 6, lane = threadIdx.x & 63;
    if (lane == 0) { red[wave * 2] = s1; red[wave * 2 + 1] = s2; }
    __syncthreads();
    if (threadIdx.x == 0) {
        float S1 = red[0] + red[2] + red[4] + red[6];
        float S2 = red[1] + red[3] + red[5] + red[7];
        float mean = S1 * (1.f / 1024.f);
        float var  = fmaxf(S2 * (1.f / 1024.f) - mean * mean, 0.f);
        stats[0] = mean;
        stats[1] = rsqrtf(var + 1e-5f);
    }
    __syncthreads();
    float mean = stats[0], inv = stats[1];
    if (*flag) {
        f32x4 o;
#pragma unroll
        for (int j = 0; j < 4; ++j) o[j] = (y[j] - mean) * inv;
        *(f32x4*)((float*)out + base) = o;
    } else {
        union { uint2 u; u16 s[4]; } o;
#pragma unroll
        for (int j = 0; j < 4; ++j) o.s[j] = f2b((y[j] - mean) * inv);
        *(uint2*)((u16*)out + base) = o.u;
    }
}

// ---------------------------------------------------------------------------
extern "C" void kernel_launch(void* const* d_in, const int* in_sizes, int n_in,
                              void* d_out, int out_size, void* d_ws, size_t ws_size,
                              hipStream_t stream) {
    // d_in[3] = src_mask, all-False per spec -> ignored
    char* ws = (char*)d_ws;
    int* flag = (int*)ws;
    u16* cx0  = (u16*)(ws + 256);                 // 8192x1024  bf16 (16 MB)
    u16* wtin = cx0  + (size_t)8192 * 1024;       // W_in^T [3072][1024] (6 MB)
    u16* wto  = wtin + (size_t)3072 * 1024;       // W_o^T  [1024][1024] (2 MB)
    u16* qkv  = wto  + (size_t)1024 * 1024;       // 8192x3072 (48 MB)
    u16* vT   = qkv  + (size_t)8192 * 3072;       // [16*64][8192] (16 MB)
    u16* attn = vT   + (size_t)1024 * 8192;       // 8192x1024 (16 MB)
    u16* proj = qkv;                              // reuse qkv region (K3 after K2)

    dim3 blk(256);
    probe_dtype<<<1, 64, 0, stream>>>((const u16*)d_in[0], flag);
    canon<<<4096, blk, 0, stream>>>(d_in[0], cx0, 8192 * 1024, flag);
    canon_t<<<dim3(16, 48), blk, 0, stream>>>(d_in[1], wtin, 1024, 3072, flag);
    canon_t<<<dim3(16, 16), blk, 0, stream>>>(d_in[2], wto,  1024, 1024, flag);
    // K1: QKV projection
    gemm_bf16<<<dim3(64, 24), blk, 0, stream>>>(cx0, wtin, qkv, 8192, 3072, 1024);
    // V pre-transpose
    vtrans<<<dim3(64, 32), blk, 0, stream>>>(qkv, vT);
    // K2: causal flash attention (paired q-tiles, XCD-swizzled)
    attn_fwd<<<dim3(16, 64), blk, 0, stream>>>(qkv, vT, attn);
    // K3: output projection
    gemm_bf16<<<dim3(64, 8), blk, 0, stream>>>(attn, wto, proj, 8192, 1024, 1024);
    // K4: residual + LayerNorm
    ln_residual<<<dim3(8192), blk, 0, stream>>>(proj, cx0, d_out, flag);
}